// Round 5
// baseline (570.848 us; speedup 1.0000x reference)
//
#include <hip/hip_runtime.h>
#include <math.h>

// ---------------------------------------------------------------------------
// SimpleGNN (4-layer GCN + mean pool + sigmoid) on MI355X.
//   - CSR build per call, XCD-affine sliced: slice = blockIdx&7 matches the
//     round-robin block->XCD dispatch, so each slice's 800KB colarr region is
//     assembled in ONE XCD's L2 -> single eviction. R5: edge streams (dst/src)
//     read with __builtin_nontemporal_load so the 12.8MB/slice streaming
//     traffic doesn't evict the partially-assembled colarr lines from L2
//     (R4: 71MB HBM writes for a 6.4MB colarr = 11x amplification).
//   - norm factored into GEMM epilogue; aggregation = pure gather-sum
//   - layers 2,3: register-tiled f32 GEMM -> bf16 gather buffer (halves the
//     819MB/layer gather traffic; f32 accumulate)
//   - layer1 reassociated (aggregate 6-dim x first); layer4 projected to
//     scalar first; pool via sorted-batch segment bounds + wave reduce
// ---------------------------------------------------------------------------

#define NSLICE 8
#define BPS 128   // blocks per slice

__global__ void hist_sliced(const int* __restrict__ dst, int* __restrict__ counts,
                            int e, int ssz) {
    const int p   = blockIdx.x & (NSLICE - 1);
    const int blk = blockIdx.x >> 3;
    const int lo = p * ssz, hi = lo + ssz;
    const int per = (e + BPS - 1) / BPS;
    const int beg = blk * per;
    const int end = min(beg + per, e);
    for (int i = beg + threadIdx.x; i < end; i += 256) {
        int d = __builtin_nontemporal_load(&dst[i]);
        if (d >= lo && d < hi) atomicAdd(&counts[d], 1);
    }
}

__global__ void scatter_sliced(const int* __restrict__ src, const int* __restrict__ dst,
                               const int* __restrict__ rowptr, int* __restrict__ cursor,
                               int* __restrict__ colarr, int e, int ssz) {
    const int p   = blockIdx.x & (NSLICE - 1);
    const int blk = blockIdx.x >> 3;
    const int lo = p * ssz, hi = lo + ssz;
    const int per = (e + BPS - 1) / BPS;
    const int beg = blk * per;
    const int end = min(beg + per, e);
    for (int i = beg + threadIdx.x; i < end; i += 256) {
        int d = __builtin_nontemporal_load(&dst[i]);
        if (d >= lo && d < hi) {
            int s = __builtin_nontemporal_load(&src[i]);
            int pos = rowptr[d] + atomicAdd(&cursor[d], 1);
            colarr[pos] = s;
        }
    }
}

__global__ void dinv_kernel(const int* __restrict__ counts, float* __restrict__ dinv, int n) {
    int i = blockIdx.x * 256 + threadIdx.x;
    if (i < n) dinv[i] = rsqrtf((float)counts[i] + 1.0f);
}

// single-block chunked exclusive scan, 4 items/thread (chunk = 4096)
__global__ void scan_kernel(const int* __restrict__ counts, int* __restrict__ rowptr, int n) {
    __shared__ int wsum[16];
    __shared__ int carry_s;
    const int tid  = threadIdx.x;            // 1024 threads
    const int lane = tid & 63, wid = tid >> 6;
    if (tid == 0) carry_s = 0;
    __syncthreads();
    const int nchunk = (n + 4095) >> 12;
    for (int c = 0; c < nchunk; ++c) {
        int i0 = (c << 12) + tid * 4;
        int4 v = make_int4(0, 0, 0, 0);
        if (i0 + 3 < n) {
            v = *(const int4*)(counts + i0);
        } else {
            if (i0     < n) v.x = counts[i0];
            if (i0 + 1 < n) v.y = counts[i0 + 1];
            if (i0 + 2 < n) v.z = counts[i0 + 2];
            if (i0 + 3 < n) v.w = counts[i0 + 3];
        }
        int s1 = v.x, s2 = s1 + v.y, s3 = s2 + v.z, s4 = s3 + v.w;
        int x = s4;
        #pragma unroll
        for (int off = 1; off < 64; off <<= 1) {
            int y = __shfl_up(x, off);
            if (lane >= off) x += y;
        }
        if (lane == 63) wsum[wid] = x;
        __syncthreads();
        if (wid == 0) {
            int s = (lane < 16) ? wsum[lane] : 0;
            #pragma unroll
            for (int off = 1; off < 16; off <<= 1) {
                int y = __shfl_up(s, off);
                if (lane >= off) s += y;
            }
            if (lane < 16) wsum[lane] = s;
        }
        __syncthreads();
        int carry = carry_s + ((wid > 0) ? wsum[wid - 1] : 0);
        int excl  = carry + x - s4;   // exclusive prefix for this thread's items
        if (i0     < n) rowptr[i0 + 1] = excl + s1;
        if (i0 + 1 < n) rowptr[i0 + 2] = excl + s2;
        if (i0 + 2 < n) rowptr[i0 + 3] = excl + s3;
        if (i0 + 3 < n) rowptr[i0 + 4] = excl + s4;
        __syncthreads();
        if (tid == 1023) carry_s = carry + x;
        __syncthreads();
    }
    if (tid == 0) rowptr[0] = 0;
}

// xs[i,c] = x[i,c] * dinv[i]
__global__ void xscale_kernel(const float* __restrict__ x, const float* __restrict__ dinv,
                              float* __restrict__ xs, int n) {
    int i = blockIdx.x * 256 + threadIdx.x;
    if (i >= n * 6) return;
    xs[i] = x[i] * dinv[i / 6];
}

// ax[i] = dinv[i] * ( sum_{s in N(i)} xs[s] + xs[i] )    (6-dim)
__global__ void aggx_kernel(const float* __restrict__ xs, const int* __restrict__ rowptr,
                            const int* __restrict__ colarr, const float* __restrict__ dinv,
                            float* __restrict__ ax, int n) {
    int i = blockIdx.x * 256 + threadIdx.x;
    if (i >= n) return;
    float a0 = 0, a1 = 0, a2 = 0, a3 = 0, a4 = 0, a5 = 0;
    int beg = rowptr[i], end = rowptr[i + 1];
    for (int e = beg; e < end; ++e) {
        int s = colarr[e];
        const float* xr = xs + (size_t)s * 6;
        a0 += xr[0]; a1 += xr[1]; a2 += xr[2];
        a3 += xr[3]; a4 += xr[4]; a5 += xr[5];
    }
    const float* xi = xs + (size_t)i * 6;
    float di = dinv[i];
    float* o = ax + (size_t)i * 6;
    o[0] = (a0 + xi[0]) * di;
    o[1] = (a1 + xi[1]) * di;
    o[2] = (a2 + xi[2]) * di;
    o[3] = (a3 + xi[3]) * di;
    o[4] = (a4 + xi[4]) * di;
    o[5] = (a5 + xi[5]) * di;
}

// h1 = relu(ax @ W1 + b1)   (6 -> 128); thread = one (node, col)
__global__ __launch_bounds__(256) void gemm1_kernel(const float* __restrict__ ax,
                                                    const float* __restrict__ W1,
                                                    const float* __restrict__ b1,
                                                    float* __restrict__ h1, int n) {
    __shared__ float Wl[6 * 128];
    __shared__ float bl[128];
    for (int i = threadIdx.x; i < 6 * 128; i += 256) Wl[i] = W1[i];
    if (threadIdx.x < 128) bl[threadIdx.x] = b1[threadIdx.x];
    __syncthreads();
    int gid = blockIdx.x * 256 + threadIdx.x;
    int node = gid >> 7, c = gid & 127;
    if (node >= n) return;
    const float* ar = ax + (size_t)node * 6;
    float acc = bl[c];
    #pragma unroll
    for (int k = 0; k < 6; ++k) acc += ar[k] * Wl[k * 128 + c];
    h1[(size_t)node * 128 + c] = fmaxf(acc, 0.0f);
}

// round-to-nearest-even f32 -> bf16
__device__ __forceinline__ unsigned short f2bf(float f) {
    unsigned u = __float_as_uint(f);
    return (unsigned short)((u + 0x7fffu + ((u >> 16) & 1u)) >> 16);
}
__device__ __forceinline__ float bf2f(unsigned short b) {
    return __uint_as_float((unsigned)b << 16);
}

// gout[node,:] = bf16( (h[node,:] @ W) * dinv[node] )
// register-tiled: 64 nodes/block, 256 threads, each 8 nodes x 4 cols
#define GN 64
__global__ __launch_bounds__(256, 4) void gemm128_reg(const float* __restrict__ h,
                                                      const float* __restrict__ W,
                                                      const float* __restrict__ dinv,
                                                      unsigned short* __restrict__ gout, int n) {
    __shared__ float Hs[GN][132];   // +4 pad: 16B-aligned rows, conflict-free reads
    const int node0 = blockIdx.x * GN;
    {
        int r  = threadIdx.x >> 5;
        int c4 = (threadIdx.x & 31) * 4;
        #pragma unroll
        for (int rr = r; rr < GN; rr += 8) {
            int node = node0 + rr;
            float4 v = make_float4(0.f, 0.f, 0.f, 0.f);
            if (node < n) v = *(const float4*)(h + (size_t)node * 128 + c4);
            *(float4*)&Hs[rr][c4] = v;
        }
    }
    __syncthreads();
    const int tx = threadIdx.x & 31;   // col group: cols 4*tx .. 4*tx+3
    const int ty = threadIdx.x >> 5;   // node group: nodes ty*8 .. ty*8+7
    float4 acc[8];
    #pragma unroll
    for (int i = 0; i < 8; ++i) acc[i] = make_float4(0.f, 0.f, 0.f, 0.f);
    const float4* Wv = (const float4*)W;   // W row k, col group tx -> Wv[k*32+tx]
    #pragma unroll 4
    for (int k4 = 0; k4 < 32; ++k4) {
        float4 w0 = Wv[(4 * k4 + 0) * 32 + tx];
        float4 w1 = Wv[(4 * k4 + 1) * 32 + tx];
        float4 w2 = Wv[(4 * k4 + 2) * 32 + tx];
        float4 w3 = Wv[(4 * k4 + 3) * 32 + tx];
        #pragma unroll
        for (int i = 0; i < 8; ++i) {
            float4 hv = *(const float4*)&Hs[ty * 8 + i][4 * k4];
            acc[i].x += hv.x * w0.x + hv.y * w1.x + hv.z * w2.x + hv.w * w3.x;
            acc[i].y += hv.x * w0.y + hv.y * w1.y + hv.z * w2.y + hv.w * w3.y;
            acc[i].z += hv.x * w0.z + hv.y * w1.z + hv.z * w2.z + hv.w * w3.z;
            acc[i].w += hv.x * w0.w + hv.y * w1.w + hv.z * w2.w + hv.w * w3.w;
        }
    }
    #pragma unroll
    for (int i = 0; i < 8; ++i) {
        int node = node0 + ty * 8 + i;
        if (node < n) {
            float dv = dinv[node];
            ushort4 o;
            o.x = f2bf(acc[i].x * dv);
            o.y = f2bf(acc[i].y * dv);
            o.z = f2bf(acc[i].z * dv);
            o.w = f2bf(acc[i].w * dv);
            *(ushort4*)(gout + (size_t)node * 128 + 4 * tx) = o;
        }
    }
}

// out[i] = relu_opt( dinv[i]*( sum_{s in N(i)} g[s] + g[i] ) + b )   (128-dim, g is bf16)
__global__ __launch_bounds__(256) void agg128_kernel(const unsigned short* __restrict__ g,
                                                     const int* __restrict__ rowptr,
                                                     const int* __restrict__ colarr,
                                                     const float* __restrict__ dinv,
                                                     const float* __restrict__ bias,
                                                     float* __restrict__ out, int n, int relu) {
    int node = blockIdx.x * 4 + (threadIdx.x >> 6);
    if (node >= n) return;
    const int lane = threadIdx.x & 63;
    const ushort2* gl = (const ushort2*)g + lane;   // row s -> gl[s*64], cols 2*lane..
    const int beg = rowptr[node], end = rowptr[node + 1];
    float ax = 0.f, ay = 0.f;
    int e = beg;
    for (; e + 3 < end; e += 4) {
        int s0 = colarr[e], s1 = colarr[e + 1], s2 = colarr[e + 2], s3 = colarr[e + 3];
        ushort2 v0 = gl[(size_t)s0 * 64];
        ushort2 v1 = gl[(size_t)s1 * 64];
        ushort2 v2 = gl[(size_t)s2 * 64];
        ushort2 v3 = gl[(size_t)s3 * 64];
        ax += (bf2f(v0.x) + bf2f(v1.x)) + (bf2f(v2.x) + bf2f(v3.x));
        ay += (bf2f(v0.y) + bf2f(v1.y)) + (bf2f(v2.y) + bf2f(v3.y));
    }
    for (; e < end; ++e) {
        ushort2 v = gl[(size_t)colarr[e] * 64];
        ax += bf2f(v.x); ay += bf2f(v.y);
    }
    ushort2 sv = gl[(size_t)node * 64];
    float2 b  = ((const float2*)bias)[lane];
    float di  = dinv[node];
    float ox = (ax + bf2f(sv.x)) * di + b.x;
    float oy = (ay + bf2f(sv.y)) * di + b.y;
    if (relu) { ox = fmaxf(ox, 0.f); oy = fmaxf(oy, 0.f); }
    ((float2*)(out + (size_t)node * 128))[lane] = make_float2(ox, oy);
}

// t[i] = dot(h[i,:], W4[:,0]) * dinv[i] ; one wave per node
__global__ void head_kernel(const float* __restrict__ h, const float* __restrict__ W4,
                            const float* __restrict__ dinv, float* __restrict__ t, int n) {
    int node = blockIdx.x * 4 + (threadIdx.x >> 6);
    if (node >= n) return;
    int lane = threadIdx.x & 63;
    float2 v = ((const float2*)(h + (size_t)node * 128))[lane];
    float2 w = ((const float2*)W4)[lane];
    float p = v.x * w.x + v.y * w.y;
    #pragma unroll
    for (int off = 32; off; off >>= 1) p += __shfl_xor(p, off);
    if (lane == 0) t[node] = p * dinv[node];
}

// s[i] = dinv[i]*( sum t[s] + t[i] ) + b4
__global__ void aggs_kernel(const float* __restrict__ t, const int* __restrict__ rowptr,
                            const int* __restrict__ colarr, const float* __restrict__ dinv,
                            const float* __restrict__ b4, float* __restrict__ s, int n) {
    int i = blockIdx.x * 256 + threadIdx.x;
    if (i >= n) return;
    float acc = 0.f;
    int beg = rowptr[i], end = rowptr[i + 1];
    int e = beg;
    for (; e + 3 < end; e += 4) {
        acc += (t[colarr[e]] + t[colarr[e + 1]]) + (t[colarr[e + 2]] + t[colarr[e + 3]]);
    }
    for (; e < end; ++e) acc += t[colarr[e]];
    s[i] = (acc + t[i]) * dinv[i] + b4[0];
}

// batch is sorted: record each graph's node range
__global__ void bounds_kernel(const int* __restrict__ batch, int* __restrict__ gstart,
                              int* __restrict__ gend, int n) {
    int i = blockIdx.x * 256 + threadIdx.x;
    if (i >= n) return;
    int g = batch[i];
    if (i == 0     || batch[i - 1] != g) gstart[g] = i;
    if (i == n - 1 || batch[i + 1] != g) gend[g]   = i + 1;
}

// one wave per graph: mean over its node range + sigmoid, straight to d_out
__global__ void pool2_kernel(const float* __restrict__ sv, const int* __restrict__ gstart,
                             const int* __restrict__ gend, float* __restrict__ out, int ng) {
    int g = blockIdx.x * 4 + (threadIdx.x >> 6);
    if (g >= ng) return;
    int lane = threadIdx.x & 63;
    int beg = gstart[g], end = gend[g];
    float acc = 0.f;
    for (int i = beg + lane; i < end; i += 64) acc += sv[i];
    #pragma unroll
    for (int off = 32; off; off >>= 1) acc += __shfl_xor(acc, off);
    if (lane == 0) {
        float c = fmaxf((float)(end - beg), 1.0f);
        float v = acc / c;
        out[g] = 1.0f / (1.0f + expf(-v));
    }
}

extern "C" void kernel_launch(void* const* d_in, const int* in_sizes, int n_in,
                              void* d_out, int out_size, void* d_ws, size_t ws_size,
                              hipStream_t stream) {
    const float* x    = (const float*)d_in[0];
    const int*   eidx = (const int*)d_in[1];
    const int*   batch= (const int*)d_in[2];
    const float* W1 = (const float*)d_in[3];
    const float* b1 = (const float*)d_in[4];
    const float* W2 = (const float*)d_in[5];
    const float* b2 = (const float*)d_in[6];
    const float* W3 = (const float*)d_in[7];
    const float* b3 = (const float*)d_in[8];
    const float* W4 = (const float*)d_in[9];
    const float* b4 = (const float*)d_in[10];

    const int n  = in_sizes[0] / 6;
    const int e  = in_sizes[1] / 2;
    const int ng = out_size;
    const int* src = eidx;
    const int* dst = eidx + e;
    const int ssz = (n + NSLICE - 1) / NSLICE;

    // workspace layout
    char* ws = (char*)d_ws;
    float* bufA   = (float*)ws; ws += (size_t)n * 128 * 4;
    unsigned short* gbuf = (unsigned short*)ws; ws += (size_t)n * 128 * 4; // bf16 uses half
    int*   colarr = (int*)ws;   ws += (size_t)e * 4;
    int*   rowptr = (int*)ws;   ws += ((size_t)n + 4) * 4;
    float* dinv   = (float*)ws; ws += (size_t)n * 4;
    int*   counts = (int*)ws;   ws += (size_t)n * 4;   // later reused as t
    int*   cursor = (int*)ws;   ws += (size_t)n * 4;   // later reused as s
    int*   gstart = (int*)ws;   ws += 1024;
    int*   gend   = (int*)ws;   ws += 1024;

    float* xs = bufA;            // [n,6] prescaled x (bufA until gemm1 writes h1)
    float* ax = (float*)gbuf;    // [n,6] aggregated (gbuf region until gemm1 consumes it)
    float* t  = (float*)counts;  // [n] after CSR build
    float* sv = (float*)cursor;  // [n] after CSR build

    const int nb = (n + 255) / 256;
    const int nw = (n + 3) / 4;       // wave-per-node kernels, 4 waves/block
    const int gb = (n + GN - 1) / GN; // gemm128_reg blocks

    // ---- CSR build (XCD-affine sliced, nt edge-stream reads) ----
    hipMemsetAsync(counts, 0, (size_t)n * 4, stream);
    hist_sliced<<<NSLICE * BPS, 256, 0, stream>>>(dst, counts, e, ssz);
    dinv_kernel<<<nb, 256, 0, stream>>>(counts, dinv, n);
    scan_kernel<<<1, 1024, 0, stream>>>(counts, rowptr, n);
    hipMemsetAsync(cursor, 0, (size_t)n * 4, stream);
    scatter_sliced<<<NSLICE * BPS, 256, 0, stream>>>(src, dst, rowptr, cursor, colarr, e, ssz);

    // ---- layer 1: prescale x, aggregate (6-dim), then GEMM ----
    xscale_kernel<<<(n * 6 + 255) / 256, 256, 0, stream>>>(x, dinv, xs, n);
    aggx_kernel<<<nb, 256, 0, stream>>>(xs, rowptr, colarr, dinv, ax, n);
    gemm1_kernel<<<(n * 128 + 255) / 256, 256, 0, stream>>>(ax, W1, b1, bufA, n);

    // ---- layer 2 ----
    gemm128_reg<<<gb, 256, 0, stream>>>(bufA, W2, dinv, gbuf, n);
    agg128_kernel<<<nw, 256, 0, stream>>>(gbuf, rowptr, colarr, dinv, b2, bufA, n, 1);

    // ---- layer 3 ----
    gemm128_reg<<<gb, 256, 0, stream>>>(bufA, W3, dinv, gbuf, n);
    agg128_kernel<<<nw, 256, 0, stream>>>(gbuf, rowptr, colarr, dinv, b3, bufA, n, 1);

    // ---- layer 4: project to scalar, aggregate ----
    head_kernel<<<nw, 256, 0, stream>>>(bufA, W4, dinv, t, n);
    aggs_kernel<<<nb, 256, 0, stream>>>(t, rowptr, colarr, dinv, b4, sv, n);

    // ---- pool: sorted batch -> segment bounds + per-graph wave mean ----
    hipMemsetAsync(gstart, 0, 2048, stream);  // covers gstart+gend (empty graphs -> [0,0))
    bounds_kernel<<<nb, 256, 0, stream>>>(batch, gstart, gend, n);
    pool2_kernel<<<(ng + 3) / 4, 256, 0, stream>>>(sv, gstart, gend, (float*)d_out, ng);
}

// Round 6
// 420.718 us; speedup vs baseline: 1.3568x; 1.3568x over previous
//
#include <hip/hip_runtime.h>
#include <math.h>

// ---------------------------------------------------------------------------
// SimpleGNN (4-layer GCN + mean pool + sigmoid) on MI355X.
//   - CSR build: ATOMIC-FREE bucket sort (R5 post-mortem: 1.6M device-scope
//     atomicAdd RMWs resolve at the memory-side coherence point -> ~51MB of
//     HBM write traffic each in hist+scatter; LDS atomics are free).
//       hist_bucket -> scan_chunks -> scan(bukBase) -> partition -> bucket_csr
//     bucket = 64 nodes; per-(chunk,bucket) offsets make placement
//     deterministic at block level; bucket_csr finishes CSR per-bucket in LDS
//     and fuses dinv.
//   - norm factored into GEMM epilogue; aggregation = pure gather-sum
//   - layers 2,3: register-tiled f32 GEMM -> bf16 gather buffer
//   - layer1 reassociated (aggregate 6-dim x first); layer4 projected to
//     scalar first; pool via sorted-batch segment bounds + wave reduce
// ---------------------------------------------------------------------------

#define BKT    64     // nodes per bucket (shift 6)
#define NCH    128    // edge chunks
#define MAXBUK 2048   // LDS capacity for bucket counters (nbuk = 1563 @ n=100k)
#define DCAP   2048   // per-bucket LDS colarr staging (mean 1024, sigma ~32)

// ---- CSR pass A: per-chunk LDS histogram over buckets ----
__global__ __launch_bounds__(256) void hist_bucket(const int* __restrict__ dst,
                                                   int* __restrict__ hmatT,
                                                   int e, int nbuk) {
    __shared__ int h[MAXBUK];
    for (int i = threadIdx.x; i < nbuk; i += 256) h[i] = 0;
    __syncthreads();
    const int per = (e + NCH - 1) / NCH;
    const int beg = blockIdx.x * per;
    const int end = min(beg + per, e);
    for (int i = beg + threadIdx.x; i < end; i += 256)
        atomicAdd(&h[dst[i] >> 6], 1);          // LDS atomic
    __syncthreads();
    for (int b = threadIdx.x; b < nbuk; b += 256)
        hmatT[b * NCH + blockIdx.x] = h[b];
}

// ---- CSR pass B1: per-bucket exclusive scan over its NCH chunk-counts ----
__global__ __launch_bounds__(256) void scan_chunks(int* __restrict__ hmatT,
                                                   int* __restrict__ totals, int nbuk) {
    int b = blockIdx.x * 4 + (threadIdx.x >> 6);
    if (b >= nbuk) return;
    const int lane = threadIdx.x & 63;
    int* row = hmatT + b * NCH;
    int v0 = row[lane], v1 = row[64 + lane];
    int x = v0;
    #pragma unroll
    for (int off = 1; off < 64; off <<= 1) { int y = __shfl_up(x, off); if (lane >= off) x += y; }
    int carry = __shfl(x, 63);
    int e0 = x - v0;
    int x1 = v1;
    #pragma unroll
    for (int off = 1; off < 64; off <<= 1) { int y = __shfl_up(x1, off); if (lane >= off) x1 += y; }
    int e1 = x1 - v1 + carry;
    int tot = __shfl(x1, 63) + carry;
    row[lane] = e0;
    row[64 + lane] = e1;
    if (lane == 0) totals[b] = tot;
}

// ---- CSR pass B2 (reused): single-block chunked exclusive scan ----
__global__ void scan_kernel(const int* __restrict__ counts, int* __restrict__ rowptr, int n) {
    __shared__ int wsum[16];
    __shared__ int carry_s;
    const int tid  = threadIdx.x;            // 1024 threads
    const int lane = tid & 63, wid = tid >> 6;
    if (tid == 0) carry_s = 0;
    __syncthreads();
    const int nchunk = (n + 4095) >> 12;
    for (int c = 0; c < nchunk; ++c) {
        int i0 = (c << 12) + tid * 4;
        int4 v = make_int4(0, 0, 0, 0);
        if (i0 + 3 < n) {
            v = *(const int4*)(counts + i0);
        } else {
            if (i0     < n) v.x = counts[i0];
            if (i0 + 1 < n) v.y = counts[i0 + 1];
            if (i0 + 2 < n) v.z = counts[i0 + 2];
            if (i0 + 3 < n) v.w = counts[i0 + 3];
        }
        int s1 = v.x, s2 = s1 + v.y, s3 = s2 + v.z, s4 = s3 + v.w;
        int x = s4;
        #pragma unroll
        for (int off = 1; off < 64; off <<= 1) {
            int y = __shfl_up(x, off);
            if (lane >= off) x += y;
        }
        if (lane == 63) wsum[wid] = x;
        __syncthreads();
        if (wid == 0) {
            int s = (lane < 16) ? wsum[lane] : 0;
            #pragma unroll
            for (int off = 1; off < 16; off <<= 1) {
                int y = __shfl_up(s, off);
                if (lane >= off) s += y;
            }
            if (lane < 16) wsum[lane] = s;
        }
        __syncthreads();
        int carry = carry_s + ((wid > 0) ? wsum[wid - 1] : 0);
        int excl  = carry + x - s4;
        if (i0     < n) rowptr[i0 + 1] = excl + s1;
        if (i0 + 1 < n) rowptr[i0 + 2] = excl + s2;
        if (i0 + 2 < n) rowptr[i0 + 3] = excl + s3;
        if (i0 + 3 < n) rowptr[i0 + 4] = excl + s4;
        __syncthreads();
        if (tid == 1023) carry_s = carry + x;
        __syncthreads();
    }
    if (tid == 0) rowptr[0] = 0;
}

// ---- CSR pass C: partition edges into bucket-grouped order (no dev atomics) ----
__global__ __launch_bounds__(256) void partition_kernel(const int* __restrict__ src,
                                                        const int* __restrict__ dst,
                                                        const int* __restrict__ hmatT,
                                                        const int* __restrict__ bukBase,
                                                        int* __restrict__ part,
                                                        int e, int nbuk) {
    __shared__ int cur[MAXBUK];
    for (int b = threadIdx.x; b < nbuk; b += 256)
        cur[b] = bukBase[b] + hmatT[b * NCH + blockIdx.x];
    __syncthreads();
    const int per = (e + NCH - 1) / NCH;
    const int beg = blockIdx.x * per;
    const int end = min(beg + per, e);
    for (int i = beg + threadIdx.x; i < end; i += 256) {
        int d = dst[i], s = src[i];
        int pos = atomicAdd(&cur[d >> 6], 1);   // LDS atomic
        part[pos] = (d & 63) | (s << 6);        // s < 2^17 -> fits
    }
}

// ---- CSR pass D: per-bucket local CSR finish + fused dinv ----
__global__ __launch_bounds__(256) void bucket_csr(const int* __restrict__ part,
                                                  const int* __restrict__ bukBase,
                                                  int* __restrict__ colarr,
                                                  int* __restrict__ rowptr,
                                                  float* __restrict__ dinv,
                                                  int n, int e) {
    __shared__ int hist[BKT];
    __shared__ int cursor[BKT];
    __shared__ int loc[DCAP];
    const int b = blockIdx.x;
    const int ebeg = bukBase[b], eend = bukBase[b + 1];
    if (threadIdx.x < BKT) hist[threadIdx.x] = 0;
    __syncthreads();
    for (int i = ebeg + threadIdx.x; i < eend; i += 256)
        atomicAdd(&hist[part[i] & (BKT - 1)], 1);
    __syncthreads();
    if (threadIdx.x < 64) {
        const int lane = threadIdx.x;
        int c = hist[lane];
        int x = c;
        #pragma unroll
        for (int off = 1; off < 64; off <<= 1) { int y = __shfl_up(x, off); if (lane >= off) x += y; }
        int excl = x - c;
        cursor[lane] = excl;
        int node = b * BKT + lane;
        if (node < n) {
            rowptr[node] = ebeg + excl;
            dinv[node]   = rsqrtf((float)c + 1.0f);
        }
    }
    if (b == 0 && threadIdx.x == 0) rowptr[n] = e;
    __syncthreads();
    for (int i = ebeg + threadIdx.x; i < eend; i += 256) {
        int p = part[i];
        int pos = atomicAdd(&cursor[p & (BKT - 1)], 1);  // LDS atomic
        int s = p >> 6;
        if (pos < DCAP) loc[pos] = s;
        else colarr[ebeg + pos] = s;   // statistically unreachable overflow path
    }
    __syncthreads();
    const int cnt = min(eend - ebeg, DCAP);
    for (int i = threadIdx.x; i < cnt; i += 256) colarr[ebeg + i] = loc[i];
}

// xs[i,c] = x[i,c] * dinv[i]
__global__ void xscale_kernel(const float* __restrict__ x, const float* __restrict__ dinv,
                              float* __restrict__ xs, int n) {
    int i = blockIdx.x * 256 + threadIdx.x;
    if (i >= n * 6) return;
    xs[i] = x[i] * dinv[i / 6];
}

// ax[i] = dinv[i] * ( sum_{s in N(i)} xs[s] + xs[i] )    (6-dim)
__global__ void aggx_kernel(const float* __restrict__ xs, const int* __restrict__ rowptr,
                            const int* __restrict__ colarr, const float* __restrict__ dinv,
                            float* __restrict__ ax, int n) {
    int i = blockIdx.x * 256 + threadIdx.x;
    if (i >= n) return;
    float a0 = 0, a1 = 0, a2 = 0, a3 = 0, a4 = 0, a5 = 0;
    int beg = rowptr[i], end = rowptr[i + 1];
    for (int e = beg; e < end; ++e) {
        int s = colarr[e];
        const float* xr = xs + (size_t)s * 6;
        a0 += xr[0]; a1 += xr[1]; a2 += xr[2];
        a3 += xr[3]; a4 += xr[4]; a5 += xr[5];
    }
    const float* xi = xs + (size_t)i * 6;
    float di = dinv[i];
    float* o = ax + (size_t)i * 6;
    o[0] = (a0 + xi[0]) * di;
    o[1] = (a1 + xi[1]) * di;
    o[2] = (a2 + xi[2]) * di;
    o[3] = (a3 + xi[3]) * di;
    o[4] = (a4 + xi[4]) * di;
    o[5] = (a5 + xi[5]) * di;
}

// h1 = relu(ax @ W1 + b1)   (6 -> 128); thread = one (node, col)
__global__ __launch_bounds__(256) void gemm1_kernel(const float* __restrict__ ax,
                                                    const float* __restrict__ W1,
                                                    const float* __restrict__ b1,
                                                    float* __restrict__ h1, int n) {
    __shared__ float Wl[6 * 128];
    __shared__ float bl[128];
    for (int i = threadIdx.x; i < 6 * 128; i += 256) Wl[i] = W1[i];
    if (threadIdx.x < 128) bl[threadIdx.x] = b1[threadIdx.x];
    __syncthreads();
    int gid = blockIdx.x * 256 + threadIdx.x;
    int node = gid >> 7, c = gid & 127;
    if (node >= n) return;
    const float* ar = ax + (size_t)node * 6;
    float acc = bl[c];
    #pragma unroll
    for (int k = 0; k < 6; ++k) acc += ar[k] * Wl[k * 128 + c];
    h1[(size_t)node * 128 + c] = fmaxf(acc, 0.0f);
}

// round-to-nearest-even f32 -> bf16
__device__ __forceinline__ unsigned short f2bf(float f) {
    unsigned u = __float_as_uint(f);
    return (unsigned short)((u + 0x7fffu + ((u >> 16) & 1u)) >> 16);
}
__device__ __forceinline__ float bf2f(unsigned short b) {
    return __uint_as_float((unsigned)b << 16);
}

// gout[node,:] = bf16( (h[node,:] @ W) * dinv[node] )
#define GN 64
__global__ __launch_bounds__(256, 4) void gemm128_reg(const float* __restrict__ h,
                                                      const float* __restrict__ W,
                                                      const float* __restrict__ dinv,
                                                      unsigned short* __restrict__ gout, int n) {
    __shared__ float Hs[GN][132];   // +4 pad
    const int node0 = blockIdx.x * GN;
    {
        int r  = threadIdx.x >> 5;
        int c4 = (threadIdx.x & 31) * 4;
        #pragma unroll
        for (int rr = r; rr < GN; rr += 8) {
            int node = node0 + rr;
            float4 v = make_float4(0.f, 0.f, 0.f, 0.f);
            if (node < n) v = *(const float4*)(h + (size_t)node * 128 + c4);
            *(float4*)&Hs[rr][c4] = v;
        }
    }
    __syncthreads();
    const int tx = threadIdx.x & 31;
    const int ty = threadIdx.x >> 5;
    float4 acc[8];
    #pragma unroll
    for (int i = 0; i < 8; ++i) acc[i] = make_float4(0.f, 0.f, 0.f, 0.f);
    const float4* Wv = (const float4*)W;
    #pragma unroll 4
    for (int k4 = 0; k4 < 32; ++k4) {
        float4 w0 = Wv[(4 * k4 + 0) * 32 + tx];
        float4 w1 = Wv[(4 * k4 + 1) * 32 + tx];
        float4 w2 = Wv[(4 * k4 + 2) * 32 + tx];
        float4 w3 = Wv[(4 * k4 + 3) * 32 + tx];
        #pragma unroll
        for (int i = 0; i < 8; ++i) {
            float4 hv = *(const float4*)&Hs[ty * 8 + i][4 * k4];
            acc[i].x += hv.x * w0.x + hv.y * w1.x + hv.z * w2.x + hv.w * w3.x;
            acc[i].y += hv.x * w0.y + hv.y * w1.y + hv.z * w2.y + hv.w * w3.y;
            acc[i].z += hv.x * w0.z + hv.y * w1.z + hv.z * w2.z + hv.w * w3.z;
            acc[i].w += hv.x * w0.w + hv.y * w1.w + hv.z * w2.w + hv.w * w3.w;
        }
    }
    #pragma unroll
    for (int i = 0; i < 8; ++i) {
        int node = node0 + ty * 8 + i;
        if (node < n) {
            float dv = dinv[node];
            ushort4 o;
            o.x = f2bf(acc[i].x * dv);
            o.y = f2bf(acc[i].y * dv);
            o.z = f2bf(acc[i].z * dv);
            o.w = f2bf(acc[i].w * dv);
            *(ushort4*)(gout + (size_t)node * 128 + 4 * tx) = o;
        }
    }
}

// out[i] = relu_opt( dinv[i]*( sum_{s in N(i)} g[s] + g[i] ) + b )   (bf16 g)
__global__ __launch_bounds__(256) void agg128_kernel(const unsigned short* __restrict__ g,
                                                     const int* __restrict__ rowptr,
                                                     const int* __restrict__ colarr,
                                                     const float* __restrict__ dinv,
                                                     const float* __restrict__ bias,
                                                     float* __restrict__ out, int n, int relu) {
    int node = blockIdx.x * 4 + (threadIdx.x >> 6);
    if (node >= n) return;
    const int lane = threadIdx.x & 63;
    const ushort2* gl = (const ushort2*)g + lane;
    const int beg = rowptr[node], end = rowptr[node + 1];
    float ax = 0.f, ay = 0.f;
    int e = beg;
    for (; e + 3 < end; e += 4) {
        int s0 = colarr[e], s1 = colarr[e + 1], s2 = colarr[e + 2], s3 = colarr[e + 3];
        ushort2 v0 = gl[(size_t)s0 * 64];
        ushort2 v1 = gl[(size_t)s1 * 64];
        ushort2 v2 = gl[(size_t)s2 * 64];
        ushort2 v3 = gl[(size_t)s3 * 64];
        ax += (bf2f(v0.x) + bf2f(v1.x)) + (bf2f(v2.x) + bf2f(v3.x));
        ay += (bf2f(v0.y) + bf2f(v1.y)) + (bf2f(v2.y) + bf2f(v3.y));
    }
    for (; e < end; ++e) {
        ushort2 v = gl[(size_t)colarr[e] * 64];
        ax += bf2f(v.x); ay += bf2f(v.y);
    }
    ushort2 sv = gl[(size_t)node * 64];
    float2 b  = ((const float2*)bias)[lane];
    float di  = dinv[node];
    float ox = (ax + bf2f(sv.x)) * di + b.x;
    float oy = (ay + bf2f(sv.y)) * di + b.y;
    if (relu) { ox = fmaxf(ox, 0.f); oy = fmaxf(oy, 0.f); }
    ((float2*)(out + (size_t)node * 128))[lane] = make_float2(ox, oy);
}

// t[i] = dot(h[i,:], W4[:,0]) * dinv[i]
__global__ void head_kernel(const float* __restrict__ h, const float* __restrict__ W4,
                            const float* __restrict__ dinv, float* __restrict__ t, int n) {
    int node = blockIdx.x * 4 + (threadIdx.x >> 6);
    if (node >= n) return;
    int lane = threadIdx.x & 63;
    float2 v = ((const float2*)(h + (size_t)node * 128))[lane];
    float2 w = ((const float2*)W4)[lane];
    float p = v.x * w.x + v.y * w.y;
    #pragma unroll
    for (int off = 32; off; off >>= 1) p += __shfl_xor(p, off);
    if (lane == 0) t[node] = p * dinv[node];
}

// s[i] = dinv[i]*( sum t[s] + t[i] ) + b4
__global__ void aggs_kernel(const float* __restrict__ t, const int* __restrict__ rowptr,
                            const int* __restrict__ colarr, const float* __restrict__ dinv,
                            const float* __restrict__ b4, float* __restrict__ s, int n) {
    int i = blockIdx.x * 256 + threadIdx.x;
    if (i >= n) return;
    float acc = 0.f;
    int beg = rowptr[i], end = rowptr[i + 1];
    int e = beg;
    for (; e + 3 < end; e += 4) {
        acc += (t[colarr[e]] + t[colarr[e + 1]]) + (t[colarr[e + 2]] + t[colarr[e + 3]]);
    }
    for (; e < end; ++e) acc += t[colarr[e]];
    s[i] = (acc + t[i]) * dinv[i] + b4[0];
}

// batch is sorted: record each graph's node range
__global__ void bounds_kernel(const int* __restrict__ batch, int* __restrict__ gstart,
                              int* __restrict__ gend, int n) {
    int i = blockIdx.x * 256 + threadIdx.x;
    if (i >= n) return;
    int g = batch[i];
    if (i == 0     || batch[i - 1] != g) gstart[g] = i;
    if (i == n - 1 || batch[i + 1] != g) gend[g]   = i + 1;
}

// one wave per graph: mean over its node range + sigmoid, straight to d_out
__global__ void pool2_kernel(const float* __restrict__ sv, const int* __restrict__ gstart,
                             const int* __restrict__ gend, float* __restrict__ out, int ng) {
    int g = blockIdx.x * 4 + (threadIdx.x >> 6);
    if (g >= ng) return;
    int lane = threadIdx.x & 63;
    int beg = gstart[g], end = gend[g];
    float acc = 0.f;
    for (int i = beg + lane; i < end; i += 64) acc += sv[i];
    #pragma unroll
    for (int off = 32; off; off >>= 1) acc += __shfl_xor(acc, off);
    if (lane == 0) {
        float c = fmaxf((float)(end - beg), 1.0f);
        float v = acc / c;
        out[g] = 1.0f / (1.0f + expf(-v));
    }
}

extern "C" void kernel_launch(void* const* d_in, const int* in_sizes, int n_in,
                              void* d_out, int out_size, void* d_ws, size_t ws_size,
                              hipStream_t stream) {
    const float* x    = (const float*)d_in[0];
    const int*   eidx = (const int*)d_in[1];
    const int*   batch= (const int*)d_in[2];
    const float* W1 = (const float*)d_in[3];
    const float* b1 = (const float*)d_in[4];
    const float* W2 = (const float*)d_in[5];
    const float* b2 = (const float*)d_in[6];
    const float* W3 = (const float*)d_in[7];
    const float* b3 = (const float*)d_in[8];
    const float* W4 = (const float*)d_in[9];
    const float* b4 = (const float*)d_in[10];

    const int n  = in_sizes[0] / 6;
    const int e  = in_sizes[1] / 2;
    const int ng = out_size;
    const int* src = eidx;
    const int* dst = eidx + e;
    const int nbuk = (n + BKT - 1) / BKT;   // 1563 @ n=100k (MAXBUK=2048 cap)

    // workspace layout
    char* ws = (char*)d_ws;
    float* bufA   = (float*)ws; ws += (size_t)n * 128 * 4;
    unsigned short* gbuf = (unsigned short*)ws; ws += (size_t)n * 128 * 4;
    int*   colarr = (int*)ws;   ws += (size_t)e * 4;
    int*   rowptr = (int*)ws;   ws += ((size_t)n + 4) * 4;
    float* dinv   = (float*)ws; ws += (size_t)n * 4;
    float* t      = (float*)ws; ws += (size_t)n * 4;
    float* sv     = (float*)ws; ws += (size_t)n * 4;
    int*   gstart = (int*)ws;   ws += 1024;
    int*   gend   = (int*)ws;   ws += 1024;

    // CSR-build scratch lives in bufA's tail (dead before gemm1 writes bufA):
    //   xs occupies bufA[0 : n*6) floats (2.4MB); scratch starts at +16MB.
    char* tail = (char*)bufA;
    int* part    = (int*)(tail + (16u << 20));           // e ints (6.4MB)
    int* hmatT   = (int*)(tail + (24u << 20));           // nbuk*NCH ints (800KB)
    int* totals  = (int*)(tail + (26u << 20));           // nbuk ints
    int* bukBase = (int*)(tail + (27u << 20));           // nbuk+1 ints

    float* xs = bufA;            // [n,6] prescaled x
    float* ax = (float*)gbuf;    // [n,6] aggregated (gbuf head until gemm1)

    const int nb = (n + 255) / 256;
    const int nw = (n + 3) / 4;
    const int gb = (n + GN - 1) / GN;

    // ---- CSR build (no device-scope atomics) ----
    hist_bucket<<<NCH, 256, 0, stream>>>(dst, hmatT, e, nbuk);
    scan_chunks<<<(nbuk + 3) / 4, 256, 0, stream>>>(hmatT, totals, nbuk);
    scan_kernel<<<1, 1024, 0, stream>>>(totals, bukBase, nbuk);
    partition_kernel<<<NCH, 256, 0, stream>>>(src, dst, hmatT, bukBase, part, e, nbuk);
    bucket_csr<<<nbuk, 256, 0, stream>>>(part, bukBase, colarr, rowptr, dinv, n, e);

    // ---- layer 1: prescale x, aggregate (6-dim), then GEMM ----
    xscale_kernel<<<(n * 6 + 255) / 256, 256, 0, stream>>>(x, dinv, xs, n);
    aggx_kernel<<<nb, 256, 0, stream>>>(xs, rowptr, colarr, dinv, ax, n);
    gemm1_kernel<<<(n * 128 + 255) / 256, 256, 0, stream>>>(ax, W1, b1, bufA, n);

    // ---- layer 2 ----
    gemm128_reg<<<gb, 256, 0, stream>>>(bufA, W2, dinv, gbuf, n);
    agg128_kernel<<<nw, 256, 0, stream>>>(gbuf, rowptr, colarr, dinv, b2, bufA, n, 1);

    // ---- layer 3 ----
    gemm128_reg<<<gb, 256, 0, stream>>>(bufA, W3, dinv, gbuf, n);
    agg128_kernel<<<nw, 256, 0, stream>>>(gbuf, rowptr, colarr, dinv, b3, bufA, n, 1);

    // ---- layer 4: project to scalar, aggregate ----
    head_kernel<<<nw, 256, 0, stream>>>(bufA, W4, dinv, t, n);
    aggs_kernel<<<nb, 256, 0, stream>>>(t, rowptr, colarr, dinv, b4, sv, n);

    // ---- pool: sorted batch -> segment bounds + per-graph wave mean ----
    hipMemsetAsync(gstart, 0, 2048, stream);
    bounds_kernel<<<nb, 256, 0, stream>>>(batch, gstart, gend, n);
    pool2_kernel<<<(ng + 3) / 4, 256, 0, stream>>>(sv, gstart, gend, (float*)d_out, ng);
}

// Round 8
// 381.124 us; speedup vs baseline: 1.4978x; 1.1039x over previous
//
#include <hip/hip_runtime.h>
#include <math.h>

// ---------------------------------------------------------------------------
// SimpleGNN (4-layer GCN + mean pool + sigmoid) on MI355X.
//   - CSR build: atomic-free bucket sort (R6: device-scope atomic RMWs were
//     ~51MB of memory-side write traffic each in hist+scatter).
//   - norm factored into GEMM epilogue; aggregation = pure gather-sum
//   - layers 2,3: register-tiled f32 GEMM -> FP8 e4m3 gather buffer (R8):
//     128B/row gathers, 12.8MB working set; agg processes 2 edges/wave
//     (32 lanes x dword) with 4x unroll = 8 edges in flight. HW cvt_pk
//     fp8<->f32. NOTE: cvt_pk builtins return native clang vectors ->
//     index with [0]/[1], not .x/.y (R7 compile fail).
//   - layer1 reassociated (aggregate 6-dim x first); layer4 projected to
//     scalar first; pool via sorted-batch segment bounds + wave reduce
// ---------------------------------------------------------------------------

#if defined(__has_builtin)
#if __has_builtin(__builtin_amdgcn_cvt_pk_f32_fp8) && __has_builtin(__builtin_amdgcn_cvt_pk_fp8_f32)
#define USE_FP8 1
#endif
#endif
#ifndef USE_FP8
#define USE_FP8 0
#endif

typedef float f32x2 __attribute__((ext_vector_type(2)));

#define BKT    64     // nodes per bucket (shift 6)
#define NCH    128    // edge chunks
#define MAXBUK 2048   // LDS capacity for bucket counters (nbuk = 1563 @ n=100k)
#define DCAP   2048   // per-bucket LDS colarr staging

// ---- CSR pass A: per-chunk LDS histogram over buckets ----
__global__ __launch_bounds__(256) void hist_bucket(const int* __restrict__ dst,
                                                   int* __restrict__ hmatT,
                                                   int e, int nbuk) {
    __shared__ int h[MAXBUK];
    for (int i = threadIdx.x; i < nbuk; i += 256) h[i] = 0;
    __syncthreads();
    const int per = (e + NCH - 1) / NCH;
    const int beg = blockIdx.x * per;
    const int end = min(beg + per, e);
    for (int i = beg + threadIdx.x; i < end; i += 256)
        atomicAdd(&h[dst[i] >> 6], 1);          // LDS atomic
    __syncthreads();
    for (int b = threadIdx.x; b < nbuk; b += 256)
        hmatT[b * NCH + blockIdx.x] = h[b];
}

// ---- CSR pass B1: per-bucket exclusive scan over its NCH chunk-counts ----
__global__ __launch_bounds__(256) void scan_chunks(int* __restrict__ hmatT,
                                                   int* __restrict__ totals, int nbuk) {
    int b = blockIdx.x * 4 + (threadIdx.x >> 6);
    if (b >= nbuk) return;
    const int lane = threadIdx.x & 63;
    int* row = hmatT + b * NCH;
    int v0 = row[lane], v1 = row[64 + lane];
    int x = v0;
    #pragma unroll
    for (int off = 1; off < 64; off <<= 1) { int y = __shfl_up(x, off); if (lane >= off) x += y; }
    int carry = __shfl(x, 63);
    int e0 = x - v0;
    int x1 = v1;
    #pragma unroll
    for (int off = 1; off < 64; off <<= 1) { int y = __shfl_up(x1, off); if (lane >= off) x1 += y; }
    int e1 = x1 - v1 + carry;
    int tot = __shfl(x1, 63) + carry;
    row[lane] = e0;
    row[64 + lane] = e1;
    if (lane == 0) totals[b] = tot;
}

// ---- CSR pass B2: single-block chunked exclusive scan ----
__global__ void scan_kernel(const int* __restrict__ counts, int* __restrict__ rowptr, int n) {
    __shared__ int wsum[16];
    __shared__ int carry_s;
    const int tid  = threadIdx.x;            // 1024 threads
    const int lane = tid & 63, wid = tid >> 6;
    if (tid == 0) carry_s = 0;
    __syncthreads();
    const int nchunk = (n + 4095) >> 12;
    for (int c = 0; c < nchunk; ++c) {
        int i0 = (c << 12) + tid * 4;
        int4 v = make_int4(0, 0, 0, 0);
        if (i0 + 3 < n) {
            v = *(const int4*)(counts + i0);
        } else {
            if (i0     < n) v.x = counts[i0];
            if (i0 + 1 < n) v.y = counts[i0 + 1];
            if (i0 + 2 < n) v.z = counts[i0 + 2];
            if (i0 + 3 < n) v.w = counts[i0 + 3];
        }
        int s1 = v.x, s2 = s1 + v.y, s3 = s2 + v.z, s4 = s3 + v.w;
        int x = s4;
        #pragma unroll
        for (int off = 1; off < 64; off <<= 1) {
            int y = __shfl_up(x, off);
            if (lane >= off) x += y;
        }
        if (lane == 63) wsum[wid] = x;
        __syncthreads();
        if (wid == 0) {
            int s = (lane < 16) ? wsum[lane] : 0;
            #pragma unroll
            for (int off = 1; off < 16; off <<= 1) {
                int y = __shfl_up(s, off);
                if (lane >= off) s += y;
            }
            if (lane < 16) wsum[lane] = s;
        }
        __syncthreads();
        int carry = carry_s + ((wid > 0) ? wsum[wid - 1] : 0);
        int excl  = carry + x - s4;
        if (i0     < n) rowptr[i0 + 1] = excl + s1;
        if (i0 + 1 < n) rowptr[i0 + 2] = excl + s2;
        if (i0 + 2 < n) rowptr[i0 + 3] = excl + s3;
        if (i0 + 3 < n) rowptr[i0 + 4] = excl + s4;
        __syncthreads();
        if (tid == 1023) carry_s = carry + x;
        __syncthreads();
    }
    if (tid == 0) rowptr[0] = 0;
}

// ---- CSR pass C: partition edges into bucket-grouped order ----
__global__ __launch_bounds__(256) void partition_kernel(const int* __restrict__ src,
                                                        const int* __restrict__ dst,
                                                        const int* __restrict__ hmatT,
                                                        const int* __restrict__ bukBase,
                                                        int* __restrict__ part,
                                                        int e, int nbuk) {
    __shared__ int cur[MAXBUK];
    for (int b = threadIdx.x; b < nbuk; b += 256)
        cur[b] = bukBase[b] + hmatT[b * NCH + blockIdx.x];
    __syncthreads();
    const int per = (e + NCH - 1) / NCH;
    const int beg = blockIdx.x * per;
    const int end = min(beg + per, e);
    for (int i = beg + threadIdx.x; i < end; i += 256) {
        int d = dst[i], s = src[i];
        int pos = atomicAdd(&cur[d >> 6], 1);   // LDS atomic
        part[pos] = (d & 63) | (s << 6);        // s < 2^17 -> fits
    }
}

// ---- CSR pass D: per-bucket local CSR finish + fused dinv ----
__global__ __launch_bounds__(256) void bucket_csr(const int* __restrict__ part,
                                                  const int* __restrict__ bukBase,
                                                  int* __restrict__ colarr,
                                                  int* __restrict__ rowptr,
                                                  float* __restrict__ dinv,
                                                  int n, int e) {
    __shared__ int hist[BKT];
    __shared__ int cursor[BKT];
    __shared__ int loc[DCAP];
    const int b = blockIdx.x;
    const int ebeg = bukBase[b], eend = bukBase[b + 1];
    if (threadIdx.x < BKT) hist[threadIdx.x] = 0;
    __syncthreads();
    for (int i = ebeg + threadIdx.x; i < eend; i += 256)
        atomicAdd(&hist[part[i] & (BKT - 1)], 1);
    __syncthreads();
    if (threadIdx.x < 64) {
        const int lane = threadIdx.x;
        int c = hist[lane];
        int x = c;
        #pragma unroll
        for (int off = 1; off < 64; off <<= 1) { int y = __shfl_up(x, off); if (lane >= off) x += y; }
        int excl = x - c;
        cursor[lane] = excl;
        int node = b * BKT + lane;
        if (node < n) {
            rowptr[node] = ebeg + excl;
            dinv[node]   = rsqrtf((float)c + 1.0f);
        }
    }
    if (b == 0 && threadIdx.x == 0) rowptr[n] = e;
    __syncthreads();
    for (int i = ebeg + threadIdx.x; i < eend; i += 256) {
        int p = part[i];
        int pos = atomicAdd(&cursor[p & (BKT - 1)], 1);  // LDS atomic
        int s = p >> 6;
        if (pos < DCAP) loc[pos] = s;
        else colarr[ebeg + pos] = s;   // statistically unreachable overflow path
    }
    __syncthreads();
    const int cnt = min(eend - ebeg, DCAP);
    for (int i = threadIdx.x; i < cnt; i += 256) colarr[ebeg + i] = loc[i];
}

// xs[i,c] = x[i,c] * dinv[i]
__global__ void xscale_kernel(const float* __restrict__ x, const float* __restrict__ dinv,
                              float* __restrict__ xs, int n) {
    int i = blockIdx.x * 256 + threadIdx.x;
    if (i >= n * 6) return;
    xs[i] = x[i] * dinv[i / 6];
}

// ax[i] = dinv[i] * ( sum_{s in N(i)} xs[s] + xs[i] )    (6-dim)
__global__ void aggx_kernel(const float* __restrict__ xs, const int* __restrict__ rowptr,
                            const int* __restrict__ colarr, const float* __restrict__ dinv,
                            float* __restrict__ ax, int n) {
    int i = blockIdx.x * 256 + threadIdx.x;
    if (i >= n) return;
    float a0 = 0, a1 = 0, a2 = 0, a3 = 0, a4 = 0, a5 = 0;
    int beg = rowptr[i], end = rowptr[i + 1];
    for (int e = beg; e < end; ++e) {
        int s = colarr[e];
        const float* xr = xs + (size_t)s * 6;
        a0 += xr[0]; a1 += xr[1]; a2 += xr[2];
        a3 += xr[3]; a4 += xr[4]; a5 += xr[5];
    }
    const float* xi = xs + (size_t)i * 6;
    float di = dinv[i];
    float* o = ax + (size_t)i * 6;
    o[0] = (a0 + xi[0]) * di;
    o[1] = (a1 + xi[1]) * di;
    o[2] = (a2 + xi[2]) * di;
    o[3] = (a3 + xi[3]) * di;
    o[4] = (a4 + xi[4]) * di;
    o[5] = (a5 + xi[5]) * di;
}

// h1 = relu(ax @ W1 + b1)   (6 -> 128); thread = one (node, col)
__global__ __launch_bounds__(256) void gemm1_kernel(const float* __restrict__ ax,
                                                    const float* __restrict__ W1,
                                                    const float* __restrict__ b1,
                                                    float* __restrict__ h1, int n) {
    __shared__ float Wl[6 * 128];
    __shared__ float bl[128];
    for (int i = threadIdx.x; i < 6 * 128; i += 256) Wl[i] = W1[i];
    if (threadIdx.x < 128) bl[threadIdx.x] = b1[threadIdx.x];
    __syncthreads();
    int gid = blockIdx.x * 256 + threadIdx.x;
    int node = gid >> 7, c = gid & 127;
    if (node >= n) return;
    const float* ar = ax + (size_t)node * 6;
    float acc = bl[c];
    #pragma unroll
    for (int k = 0; k < 6; ++k) acc += ar[k] * Wl[k * 128 + c];
    h1[(size_t)node * 128 + c] = fmaxf(acc, 0.0f);
}

// round-to-nearest-even f32 -> bf16 (bf16 fallback path)
__device__ __forceinline__ unsigned short f2bf(float f) {
    unsigned u = __float_as_uint(f);
    return (unsigned short)((u + 0x7fffu + ((u >> 16) & 1u)) >> 16);
}
__device__ __forceinline__ float bf2f(unsigned short b) {
    return __uint_as_float((unsigned)b << 16);
}

// gout[node,:] = lowp( (h[node,:] @ W) * dinv[node] )
// register-tiled: 64 nodes/block, 256 threads, each 8 nodes x 4 cols
#define GN 64
__global__ __launch_bounds__(256, 4) void gemm128_reg(const float* __restrict__ h,
                                                      const float* __restrict__ W,
                                                      const float* __restrict__ dinv,
                                                      void* __restrict__ gout, int n) {
    __shared__ float Hs[GN][132];   // +4 pad
    const int node0 = blockIdx.x * GN;
    {
        int r  = threadIdx.x >> 5;
        int c4 = (threadIdx.x & 31) * 4;
        #pragma unroll
        for (int rr = r; rr < GN; rr += 8) {
            int node = node0 + rr;
            float4 v = make_float4(0.f, 0.f, 0.f, 0.f);
            if (node < n) v = *(const float4*)(h + (size_t)node * 128 + c4);
            *(float4*)&Hs[rr][c4] = v;
        }
    }
    __syncthreads();
    const int tx = threadIdx.x & 31;
    const int ty = threadIdx.x >> 5;
    float4 acc[8];
    #pragma unroll
    for (int i = 0; i < 8; ++i) acc[i] = make_float4(0.f, 0.f, 0.f, 0.f);
    const float4* Wv = (const float4*)W;
    #pragma unroll 4
    for (int k4 = 0; k4 < 32; ++k4) {
        float4 w0 = Wv[(4 * k4 + 0) * 32 + tx];
        float4 w1 = Wv[(4 * k4 + 1) * 32 + tx];
        float4 w2 = Wv[(4 * k4 + 2) * 32 + tx];
        float4 w3 = Wv[(4 * k4 + 3) * 32 + tx];
        #pragma unroll
        for (int i = 0; i < 8; ++i) {
            float4 hv = *(const float4*)&Hs[ty * 8 + i][4 * k4];
            acc[i].x += hv.x * w0.x + hv.y * w1.x + hv.z * w2.x + hv.w * w3.x;
            acc[i].y += hv.x * w0.y + hv.y * w1.y + hv.z * w2.y + hv.w * w3.y;
            acc[i].z += hv.x * w0.z + hv.y * w1.z + hv.z * w2.z + hv.w * w3.z;
            acc[i].w += hv.x * w0.w + hv.y * w1.w + hv.z * w2.w + hv.w * w3.w;
        }
    }
    #pragma unroll
    for (int i = 0; i < 8; ++i) {
        int node = node0 + ty * 8 + i;
        if (node < n) {
            float dv = dinv[node];
#if USE_FP8
            int w = __builtin_amdgcn_cvt_pk_fp8_f32(acc[i].x * dv, acc[i].y * dv, 0, false);
            w     = __builtin_amdgcn_cvt_pk_fp8_f32(acc[i].z * dv, acc[i].w * dv, w, true);
            ((int*)gout)[(size_t)node * 32 + tx] = w;           // 128B fp8 row
#else
            ushort4 o;
            o.x = f2bf(acc[i].x * dv);
            o.y = f2bf(acc[i].y * dv);
            o.z = f2bf(acc[i].z * dv);
            o.w = f2bf(acc[i].w * dv);
            ((ushort4*)gout)[(size_t)node * 32 + tx] = o;       // 256B bf16 row
#endif
        }
    }
}

#if USE_FP8
// out[i] = relu_opt( dinv[i]*( sum_{s in N(i)} g[s] + g[i] ) + b )   (fp8 g)
// 32 lanes x 1 dword (4 fp8) per row; lane>>5 picks edge of a pair; 4x unroll.
__global__ __launch_bounds__(256) void agg128_kernel(const void* __restrict__ g,
                                                     const int* __restrict__ rowptr,
                                                     const int* __restrict__ colarr,
                                                     const float* __restrict__ dinv,
                                                     const float* __restrict__ bias,
                                                     float* __restrict__ out, int n, int relu) {
    int node = blockIdx.x * 4 + (threadIdx.x >> 6);
    if (node >= n) return;
    const int lane = threadIdx.x & 63;
    const int half = lane >> 5;        // edge-in-pair
    const int c    = lane & 31;        // dword index within row
    const int* gi = (const int*)g;     // row s -> gi[s*32 + c]
    const int beg = rowptr[node], end = rowptr[node + 1];
    float ax = 0.f, ay = 0.f, az = 0.f, aw = 0.f;
    int e = beg;
    // main loop: 8 edges (4 gathers in flight per wave), no guards
    for (; e + 8 <= end; e += 8) {
        int s0 = colarr[e     + half];
        int s1 = colarr[e + 2 + half];
        int s2 = colarr[e + 4 + half];
        int s3 = colarr[e + 6 + half];
        int w0 = gi[(size_t)s0 * 32 + c];
        int w1 = gi[(size_t)s1 * 32 + c];
        int w2 = gi[(size_t)s2 * 32 + c];
        int w3 = gi[(size_t)s3 * 32 + c];
        f32x2 l0 = __builtin_amdgcn_cvt_pk_f32_fp8(w0, false);
        f32x2 h0 = __builtin_amdgcn_cvt_pk_f32_fp8(w0, true);
        f32x2 l1 = __builtin_amdgcn_cvt_pk_f32_fp8(w1, false);
        f32x2 h1 = __builtin_amdgcn_cvt_pk_f32_fp8(w1, true);
        f32x2 l2 = __builtin_amdgcn_cvt_pk_f32_fp8(w2, false);
        f32x2 h2 = __builtin_amdgcn_cvt_pk_f32_fp8(w2, true);
        f32x2 l3 = __builtin_amdgcn_cvt_pk_f32_fp8(w3, false);
        f32x2 h3 = __builtin_amdgcn_cvt_pk_f32_fp8(w3, true);
        ax += (l0[0] + l1[0]) + (l2[0] + l3[0]);
        ay += (l0[1] + l1[1]) + (l2[1] + l3[1]);
        az += (h0[0] + h1[0]) + (h2[0] + h3[0]);
        aw += (h0[1] + h1[1]) + (h2[1] + h3[1]);
    }
    // tail: pairs with predication
    for (; e < end; e += 2) {
        int idx = e + half;
        int w = 0;
        if (idx < end) {
            int s = colarr[idx];
            w = gi[(size_t)s * 32 + c];
        }
        f32x2 lo = __builtin_amdgcn_cvt_pk_f32_fp8(w, false);
        f32x2 hi = __builtin_amdgcn_cvt_pk_f32_fp8(w, true);
        ax += lo[0]; ay += lo[1]; az += hi[0]; aw += hi[1];
    }
    // cross-half reduce: combine the two edge-halves
    ax += __shfl_xor(ax, 32);
    ay += __shfl_xor(ay, 32);
    az += __shfl_xor(az, 32);
    aw += __shfl_xor(aw, 32);
    if (lane < 32) {
        int wsv = gi[(size_t)node * 32 + lane];
        f32x2 slo = __builtin_amdgcn_cvt_pk_f32_fp8(wsv, false);
        f32x2 shi = __builtin_amdgcn_cvt_pk_f32_fp8(wsv, true);
        float4 b = ((const float4*)bias)[lane];
        float di = dinv[node];
        float ox = (ax + slo[0]) * di + b.x;
        float oy = (ay + slo[1]) * di + b.y;
        float oz = (az + shi[0]) * di + b.z;
        float ow = (aw + shi[1]) * di + b.w;
        if (relu) {
            ox = fmaxf(ox, 0.f); oy = fmaxf(oy, 0.f);
            oz = fmaxf(oz, 0.f); ow = fmaxf(ow, 0.f);
        }
        ((float4*)(out + (size_t)node * 128))[lane] = make_float4(ox, oy, oz, ow);
    }
}
#else
// bf16 fallback (R6 path)
__global__ __launch_bounds__(256) void agg128_kernel(const void* __restrict__ g,
                                                     const int* __restrict__ rowptr,
                                                     const int* __restrict__ colarr,
                                                     const float* __restrict__ dinv,
                                                     const float* __restrict__ bias,
                                                     float* __restrict__ out, int n, int relu) {
    int node = blockIdx.x * 4 + (threadIdx.x >> 6);
    if (node >= n) return;
    const int lane = threadIdx.x & 63;
    const ushort2* gl = (const ushort2*)g + lane;
    const int beg = rowptr[node], end = rowptr[node + 1];
    float ax = 0.f, ay = 0.f;
    int e = beg;
    for (; e + 3 < end; e += 4) {
        int s0 = colarr[e], s1 = colarr[e + 1], s2 = colarr[e + 2], s3 = colarr[e + 3];
        ushort2 v0 = gl[(size_t)s0 * 64];
        ushort2 v1 = gl[(size_t)s1 * 64];
        ushort2 v2 = gl[(size_t)s2 * 64];
        ushort2 v3 = gl[(size_t)s3 * 64];
        ax += (bf2f(v0.x) + bf2f(v1.x)) + (bf2f(v2.x) + bf2f(v3.x));
        ay += (bf2f(v0.y) + bf2f(v1.y)) + (bf2f(v2.y) + bf2f(v3.y));
    }
    for (; e < end; ++e) {
        ushort2 v = gl[(size_t)colarr[e] * 64];
        ax += bf2f(v.x); ay += bf2f(v.y);
    }
    ushort2 svv = gl[(size_t)node * 64];
    float2 b  = ((const float2*)bias)[lane];
    float di  = dinv[node];
    float ox = (ax + bf2f(svv.x)) * di + b.x;
    float oy = (ay + bf2f(svv.y)) * di + b.y;
    if (relu) { ox = fmaxf(ox, 0.f); oy = fmaxf(oy, 0.f); }
    ((float2*)(out + (size_t)node * 128))[lane] = make_float2(ox, oy);
}
#endif

// t[i] = dot(h[i,:], W4[:,0]) * dinv[i]
__global__ void head_kernel(const float* __restrict__ h, const float* __restrict__ W4,
                            const float* __restrict__ dinv, float* __restrict__ t, int n) {
    int node = blockIdx.x * 4 + (threadIdx.x >> 6);
    if (node >= n) return;
    int lane = threadIdx.x & 63;
    float2 v = ((const float2*)(h + (size_t)node * 128))[lane];
    float2 w = ((const float2*)W4)[lane];
    float p = v.x * w.x + v.y * w.y;
    #pragma unroll
    for (int off = 32; off; off >>= 1) p += __shfl_xor(p, off);
    if (lane == 0) t[node] = p * dinv[node];
}

// s[i] = dinv[i]*( sum t[s] + t[i] ) + b4
__global__ void aggs_kernel(const float* __restrict__ t, const int* __restrict__ rowptr,
                            const int* __restrict__ colarr, const float* __restrict__ dinv,
                            const float* __restrict__ b4, float* __restrict__ s, int n) {
    int i = blockIdx.x * 256 + threadIdx.x;
    if (i >= n) return;
    float acc = 0.f;
    int beg = rowptr[i], end = rowptr[i + 1];
    int e = beg;
    for (; e + 3 < end; e += 4) {
        acc += (t[colarr[e]] + t[colarr[e + 1]]) + (t[colarr[e + 2]] + t[colarr[e + 3]]);
    }
    for (; e < end; ++e) acc += t[colarr[e]];
    s[i] = (acc + t[i]) * dinv[i] + b4[0];
}

// batch is sorted: record each graph's node range
__global__ void bounds_kernel(const int* __restrict__ batch, int* __restrict__ gstart,
                              int* __restrict__ gend, int n) {
    int i = blockIdx.x * 256 + threadIdx.x;
    if (i >= n) return;
    int g = batch[i];
    if (i == 0     || batch[i - 1] != g) gstart[g] = i;
    if (i == n - 1 || batch[i + 1] != g) gend[g]   = i + 1;
}

// one wave per graph: mean over its node range + sigmoid, straight to d_out
__global__ void pool2_kernel(const float* __restrict__ sv, const int* __restrict__ gstart,
                             const int* __restrict__ gend, float* __restrict__ out, int ng) {
    int g = blockIdx.x * 4 + (threadIdx.x >> 6);
    if (g >= ng) return;
    int lane = threadIdx.x & 63;
    int beg = gstart[g], end = gend[g];
    float acc = 0.f;
    for (int i = beg + lane; i < end; i += 64) acc += sv[i];
    #pragma unroll
    for (int off = 32; off; off >>= 1) acc += __shfl_xor(acc, off);
    if (lane == 0) {
        float c = fmaxf((float)(end - beg), 1.0f);
        float v = acc / c;
        out[g] = 1.0f / (1.0f + expf(-v));
    }
}

extern "C" void kernel_launch(void* const* d_in, const int* in_sizes, int n_in,
                              void* d_out, int out_size, void* d_ws, size_t ws_size,
                              hipStream_t stream) {
    const float* x    = (const float*)d_in[0];
    const int*   eidx = (const int*)d_in[1];
    const int*   batch= (const int*)d_in[2];
    const float* W1 = (const float*)d_in[3];
    const float* b1 = (const float*)d_in[4];
    const float* W2 = (const float*)d_in[5];
    const float* b2 = (const float*)d_in[6];
    const float* W3 = (const float*)d_in[7];
    const float* b3 = (const float*)d_in[8];
    const float* W4 = (const float*)d_in[9];
    const float* b4 = (const float*)d_in[10];

    const int n  = in_sizes[0] / 6;
    const int e  = in_sizes[1] / 2;
    const int ng = out_size;
    const int* src = eidx;
    const int* dst = eidx + e;
    const int nbuk = (n + BKT - 1) / BKT;   // 1563 @ n=100k (MAXBUK=2048 cap)

    // workspace layout
    char* ws = (char*)d_ws;
    float* bufA   = (float*)ws; ws += (size_t)n * 128 * 4;
    void*  gbuf   = (void*)ws;  ws += (size_t)n * 128 * 4;  // fp8 uses 1/4
    int*   colarr = (int*)ws;   ws += (size_t)e * 4;
    int*   rowptr = (int*)ws;   ws += ((size_t)n + 4) * 4;
    float* dinv   = (float*)ws; ws += (size_t)n * 4;
    float* t      = (float*)ws; ws += (size_t)n * 4;
    float* sv     = (float*)ws; ws += (size_t)n * 4;
    int*   gstart = (int*)ws;   ws += 1024;
    int*   gend   = (int*)ws;   ws += 1024;

    // CSR-build scratch lives in bufA's tail (dead before gemm1 writes bufA):
    char* tail = (char*)bufA;
    int* part    = (int*)(tail + (16u << 20));           // e ints (6.4MB)
    int* hmatT   = (int*)(tail + (24u << 20));           // nbuk*NCH ints
    int* totals  = (int*)(tail + (26u << 20));           // nbuk ints
    int* bukBase = (int*)(tail + (27u << 20));           // nbuk+1 ints

    float* xs = bufA;            // [n,6] prescaled x
    float* ax = (float*)gbuf;    // [n,6] aggregated (gbuf head until gemm1)

    const int nb = (n + 255) / 256;
    const int nw = (n + 3) / 4;
    const int gb = (n + GN - 1) / GN;

    // ---- CSR build (no device-scope atomics) ----
    hist_bucket<<<NCH, 256, 0, stream>>>(dst, hmatT, e, nbuk);
    scan_chunks<<<(nbuk + 3) / 4, 256, 0, stream>>>(hmatT, totals, nbuk);
    scan_kernel<<<1, 1024, 0, stream>>>(totals, bukBase, nbuk);
    partition_kernel<<<NCH, 256, 0, stream>>>(src, dst, hmatT, bukBase, part, e, nbuk);
    bucket_csr<<<nbuk, 256, 0, stream>>>(part, bukBase, colarr, rowptr, dinv, n, e);

    // ---- layer 1: prescale x, aggregate (6-dim), then GEMM ----
    xscale_kernel<<<(n * 6 + 255) / 256, 256, 0, stream>>>(x, dinv, xs, n);
    aggx_kernel<<<nb, 256, 0, stream>>>(xs, rowptr, colarr, dinv, ax, n);
    gemm1_kernel<<<(n * 128 + 255) / 256, 256, 0, stream>>>(ax, W1, b1, bufA, n);

    // ---- layer 2 ----
    gemm128_reg<<<gb, 256, 0, stream>>>(bufA, W2, dinv, gbuf, n);
    agg128_kernel<<<nw, 256, 0, stream>>>(gbuf, rowptr, colarr, dinv, b2, bufA, n, 1);

    // ---- layer 3 ----
    gemm128_reg<<<gb, 256, 0, stream>>>(bufA, W3, dinv, gbuf, n);
    agg128_kernel<<<nw, 256, 0, stream>>>(gbuf, rowptr, colarr, dinv, b3, bufA, n, 1);

    // ---- layer 4: project to scalar, aggregate ----
    head_kernel<<<nw, 256, 0, stream>>>(bufA, W4, dinv, t, n);
    aggs_kernel<<<nb, 256, 0, stream>>>(t, rowptr, colarr, dinv, b4, sv, n);

    // ---- pool: sorted batch -> segment bounds + per-graph wave mean ----
    hipMemsetAsync(gstart, 0, 2048, stream);
    bounds_kernel<<<nb, 256, 0, stream>>>(batch, gstart, gend, n);
    pool2_kernel<<<(ng + 3) / 4, 256, 0, stream>>>(sv, gstart, gend, (float*)d_out, ng);
}

// Round 9
// 297.780 us; speedup vs baseline: 1.9170x; 1.2799x over previous
//
#include <hip/hip_runtime.h>
#include <math.h>

// ---------------------------------------------------------------------------
// SimpleGNN (4-layer GCN + mean pool + sigmoid) on MI355X.
//   - CSR build: atomic-free bucket sort (R6).
//   - norm factored into GEMM epilogue; aggregation = pure gather-sum
//   - h kept in BF16 (R9); layers 2,3 = bf16 MFMA GEMM (16x16x32) -> FP8
//     gather buffer (R8: 128B/row gathers). agg: 2 edges/wave, 4x unroll,
//     f32 accumulate, writes bf16 h.
//   - layer1 reassociated (aggregate 6-dim x first); layer4 projected to
//     scalar first; pool via sorted-batch segment bounds + wave reduce
// ---------------------------------------------------------------------------

typedef float f32x2 __attribute__((ext_vector_type(2)));
typedef float f32x4 __attribute__((ext_vector_type(4)));
typedef short bf16x8 __attribute__((ext_vector_type(8)));   // 8 bf16 = 4 VGPRs

#define BKT    64     // nodes per bucket (shift 6)
#define NCH    128    // edge chunks
#define MAXBUK 2048   // LDS bucket counters (nbuk = 1563 @ n=100k)
#define DCAP   2048   // per-bucket LDS colarr staging
#define WTP    136    // padded row length of transposed W (bf16)

// ---- CSR pass A: per-chunk LDS histogram over buckets ----
__global__ __launch_bounds__(256) void hist_bucket(const int* __restrict__ dst,
                                                   int* __restrict__ hmatT,
                                                   int e, int nbuk) {
    __shared__ int h[MAXBUK];
    for (int i = threadIdx.x; i < nbuk; i += 256) h[i] = 0;
    __syncthreads();
    const int per = (e + NCH - 1) / NCH;
    const int beg = blockIdx.x * per;
    const int end = min(beg + per, e);
    for (int i = beg + threadIdx.x; i < end; i += 256)
        atomicAdd(&h[dst[i] >> 6], 1);          // LDS atomic
    __syncthreads();
    for (int b = threadIdx.x; b < nbuk; b += 256)
        hmatT[b * NCH + blockIdx.x] = h[b];
}

// ---- CSR pass B1: per-bucket exclusive scan over its NCH chunk-counts ----
__global__ __launch_bounds__(256) void scan_chunks(int* __restrict__ hmatT,
                                                   int* __restrict__ totals, int nbuk) {
    int b = blockIdx.x * 4 + (threadIdx.x >> 6);
    if (b >= nbuk) return;
    const int lane = threadIdx.x & 63;
    int* row = hmatT + b * NCH;
    int v0 = row[lane], v1 = row[64 + lane];
    int x = v0;
    #pragma unroll
    for (int off = 1; off < 64; off <<= 1) { int y = __shfl_up(x, off); if (lane >= off) x += y; }
    int carry = __shfl(x, 63);
    int e0 = x - v0;
    int x1 = v1;
    #pragma unroll
    for (int off = 1; off < 64; off <<= 1) { int y = __shfl_up(x1, off); if (lane >= off) x1 += y; }
    int e1 = x1 - v1 + carry;
    int tot = __shfl(x1, 63) + carry;
    row[lane] = e0;
    row[64 + lane] = e1;
    if (lane == 0) totals[b] = tot;
}

// ---- CSR pass B2: single-block chunked exclusive scan ----
__global__ void scan_kernel(const int* __restrict__ counts, int* __restrict__ rowptr, int n) {
    __shared__ int wsum[16];
    __shared__ int carry_s;
    const int tid  = threadIdx.x;            // 1024 threads
    const int lane = tid & 63, wid = tid >> 6;
    if (tid == 0) carry_s = 0;
    __syncthreads();
    const int nchunk = (n + 4095) >> 12;
    for (int c = 0; c < nchunk; ++c) {
        int i0 = (c << 12) + tid * 4;
        int4 v = make_int4(0, 0, 0, 0);
        if (i0 + 3 < n) {
            v = *(const int4*)(counts + i0);
        } else {
            if (i0     < n) v.x = counts[i0];
            if (i0 + 1 < n) v.y = counts[i0 + 1];
            if (i0 + 2 < n) v.z = counts[i0 + 2];
            if (i0 + 3 < n) v.w = counts[i0 + 3];
        }
        int s1 = v.x, s2 = s1 + v.y, s3 = s2 + v.z, s4 = s3 + v.w;
        int x = s4;
        #pragma unroll
        for (int off = 1; off < 64; off <<= 1) {
            int y = __shfl_up(x, off);
            if (lane >= off) x += y;
        }
        if (lane == 63) wsum[wid] = x;
        __syncthreads();
        if (wid == 0) {
            int s = (lane < 16) ? wsum[lane] : 0;
            #pragma unroll
            for (int off = 1; off < 16; off <<= 1) {
                int y = __shfl_up(s, off);
                if (lane >= off) s += y;
            }
            if (lane < 16) wsum[lane] = s;
        }
        __syncthreads();
        int carry = carry_s + ((wid > 0) ? wsum[wid - 1] : 0);
        int excl  = carry + x - s4;
        if (i0     < n) rowptr[i0 + 1] = excl + s1;
        if (i0 + 1 < n) rowptr[i0 + 2] = excl + s2;
        if (i0 + 2 < n) rowptr[i0 + 3] = excl + s3;
        if (i0 + 3 < n) rowptr[i0 + 4] = excl + s4;
        __syncthreads();
        if (tid == 1023) carry_s = carry + x;
        __syncthreads();
    }
    if (tid == 0) rowptr[0] = 0;
}

// ---- CSR pass C: partition edges into bucket-grouped order ----
__global__ __launch_bounds__(256) void partition_kernel(const int* __restrict__ src,
                                                        const int* __restrict__ dst,
                                                        const int* __restrict__ hmatT,
                                                        const int* __restrict__ bukBase,
                                                        int* __restrict__ part,
                                                        int e, int nbuk) {
    __shared__ int cur[MAXBUK];
    for (int b = threadIdx.x; b < nbuk; b += 256)
        cur[b] = bukBase[b] + hmatT[b * NCH + blockIdx.x];
    __syncthreads();
    const int per = (e + NCH - 1) / NCH;
    const int beg = blockIdx.x * per;
    const int end = min(beg + per, e);
    for (int i = beg + threadIdx.x; i < end; i += 256) {
        int d = dst[i], s = src[i];
        int pos = atomicAdd(&cur[d >> 6], 1);   // LDS atomic
        part[pos] = (d & 63) | (s << 6);        // s < 2^17 -> fits
    }
}

// ---- CSR pass D: per-bucket local CSR finish + fused dinv ----
__global__ __launch_bounds__(256) void bucket_csr(const int* __restrict__ part,
                                                  const int* __restrict__ bukBase,
                                                  int* __restrict__ colarr,
                                                  int* __restrict__ rowptr,
                                                  float* __restrict__ dinv,
                                                  int n, int e) {
    __shared__ int hist[BKT];
    __shared__ int cursor[BKT];
    __shared__ int loc[DCAP];
    const int b = blockIdx.x;
    const int ebeg = bukBase[b], eend = bukBase[b + 1];
    if (threadIdx.x < BKT) hist[threadIdx.x] = 0;
    __syncthreads();
    for (int i = ebeg + threadIdx.x; i < eend; i += 256)
        atomicAdd(&hist[part[i] & (BKT - 1)], 1);
    __syncthreads();
    if (threadIdx.x < 64) {
        const int lane = threadIdx.x;
        int c = hist[lane];
        int x = c;
        #pragma unroll
        for (int off = 1; off < 64; off <<= 1) { int y = __shfl_up(x, off); if (lane >= off) x += y; }
        int excl = x - c;
        cursor[lane] = excl;
        int node = b * BKT + lane;
        if (node < n) {
            rowptr[node] = ebeg + excl;
            dinv[node]   = rsqrtf((float)c + 1.0f);
        }
    }
    if (b == 0 && threadIdx.x == 0) rowptr[n] = e;
    __syncthreads();
    for (int i = ebeg + threadIdx.x; i < eend; i += 256) {
        int p = part[i];
        int pos = atomicAdd(&cursor[p & (BKT - 1)], 1);  // LDS atomic
        int s = p >> 6;
        if (pos < DCAP) loc[pos] = s;
        else colarr[ebeg + pos] = s;   // statistically unreachable overflow path
    }
    __syncthreads();
    const int cnt = min(eend - ebeg, DCAP);
    for (int i = threadIdx.x; i < cnt; i += 256) colarr[ebeg + i] = loc[i];
}

// xs[i,c] = x[i,c] * dinv[i]
__global__ void xscale_kernel(const float* __restrict__ x, const float* __restrict__ dinv,
                              float* __restrict__ xs, int n) {
    int i = blockIdx.x * 256 + threadIdx.x;
    if (i >= n * 6) return;
    xs[i] = x[i] * dinv[i / 6];
}

// ax[i] = dinv[i] * ( sum_{s in N(i)} xs[s] + xs[i] )    (6-dim)
__global__ void aggx_kernel(const float* __restrict__ xs, const int* __restrict__ rowptr,
                            const int* __restrict__ colarr, const float* __restrict__ dinv,
                            float* __restrict__ ax, int n) {
    int i = blockIdx.x * 256 + threadIdx.x;
    if (i >= n) return;
    float a0 = 0, a1 = 0, a2 = 0, a3 = 0, a4 = 0, a5 = 0;
    int beg = rowptr[i], end = rowptr[i + 1];
    for (int e = beg; e < end; ++e) {
        int s = colarr[e];
        const float* xr = xs + (size_t)s * 6;
        a0 += xr[0]; a1 += xr[1]; a2 += xr[2];
        a3 += xr[3]; a4 += xr[4]; a5 += xr[5];
    }
    const float* xi = xs + (size_t)i * 6;
    float di = dinv[i];
    float* o = ax + (size_t)i * 6;
    o[0] = (a0 + xi[0]) * di;
    o[1] = (a1 + xi[1]) * di;
    o[2] = (a2 + xi[2]) * di;
    o[3] = (a3 + xi[3]) * di;
    o[4] = (a4 + xi[4]) * di;
    o[5] = (a5 + xi[5]) * di;
}

// round-to-nearest-even f32 -> bf16
__device__ __forceinline__ unsigned short f2bf(float f) {
    unsigned u = __float_as_uint(f);
    return (unsigned short)((u + 0x7fffu + ((u >> 16) & 1u)) >> 16);
}
__device__ __forceinline__ float bf2f(unsigned short b) {
    return __uint_as_float((unsigned)b << 16);
}

// h1 = bf16( relu(ax @ W1 + b1) )   (6 -> 128); thread = one (node, col)
__global__ __launch_bounds__(256) void gemm1_kernel(const float* __restrict__ ax,
                                                    const float* __restrict__ W1,
                                                    const float* __restrict__ b1,
                                                    unsigned short* __restrict__ h1, int n) {
    __shared__ float Wl[6 * 128];
    __shared__ float bl[128];
    for (int i = threadIdx.x; i < 6 * 128; i += 256) Wl[i] = W1[i];
    if (threadIdx.x < 128) bl[threadIdx.x] = b1[threadIdx.x];
    __syncthreads();
    int gid = blockIdx.x * 256 + threadIdx.x;
    int node = gid >> 7, c = gid & 127;
    if (node >= n) return;
    const float* ar = ax + (size_t)node * 6;
    float acc = bl[c];
    #pragma unroll
    for (int k = 0; k < 6; ++k) acc += ar[k] * Wl[k * 128 + c];
    h1[(size_t)node * 128 + c] = f2bf(fmaxf(acc, 0.0f));
}

// W (f32 [128][128], row k = input dim) -> wtg (bf16 [col][k], padded rows WTP)
__global__ void wconv_kernel(const float* __restrict__ W, unsigned short* __restrict__ wtg) {
    int idx = blockIdx.x * 256 + threadIdx.x;
    if (idx >= 128 * 128) return;
    int k = idx >> 7, c = idx & 127;
    wtg[c * WTP + k] = f2bf(W[idx]);
}

// gout[node,:] = fp8( (hb[node,:] @ W) * dinv[node] )   via bf16 MFMA
// block = 256 threads = 4 waves; wave -> 16 nodes x 128 cols; K=128.
#define MB 64   // nodes per block
__global__ __launch_bounds__(256) void gemm128_mfma(const unsigned short* __restrict__ hb,
                                                    const unsigned short* __restrict__ wtg,
                                                    const float* __restrict__ dinv,
                                                    int* __restrict__ gout, int n) {
    __shared__ unsigned short Wt[128 * WTP];   // 34.8 KB, transposed W
    __shared__ float dl[MB];
    __shared__ float ctile[4][16][16];         // per-wave epilogue repack
    const int tid = threadIdx.x;
    const int node0 = blockIdx.x * MB;
    {   // stage Wt: straight 16B copies (wtg already transposed+padded)
        const int4* s4 = (const int4*)wtg;
        int4* d4 = (int4*)Wt;
        for (int i = tid; i < 128 * WTP * 2 / 16; i += 256) d4[i] = s4[i];
    }
    if (tid < MB) {
        int node = node0 + tid;
        dl[tid] = (node < n) ? dinv[node] : 0.f;
    }
    __syncthreads();
    const int wid  = tid >> 6, lane = tid & 63;
    const int wn0  = node0 + wid * 16;          // this wave's 16 nodes
    const int arow = wn0 + (lane & 15);         // A row for this lane (hb has slack)
    const int koff = (lane >> 4) * 8;           // k-chunk within 32
    // A fragments: K=128 in 4 chunks of 32 (each lane: 8 contiguous bf16)
    bf16x8 a0 = *(const bf16x8*)(hb + (size_t)arow * 128 +  0 + koff);
    bf16x8 a1 = *(const bf16x8*)(hb + (size_t)arow * 128 + 32 + koff);
    bf16x8 a2 = *(const bf16x8*)(hb + (size_t)arow * 128 + 64 + koff);
    bf16x8 a3 = *(const bf16x8*)(hb + (size_t)arow * 128 + 96 + koff);
    const int crow = (lane >> 4) * 2;           // C/D: row=(l>>4)*4+reg, col=l&15
    const int ccol = lane & 15;
    float* ct = &ctile[wid][0][0];
    #pragma unroll
    for (int nt = 0; nt < 8; ++nt) {            // 16-col output tiles
        const unsigned short* wb = Wt + (size_t)(nt * 16 + (lane & 15)) * WTP + koff;
        f32x4 c = {0.f, 0.f, 0.f, 0.f};
        c = __builtin_amdgcn_mfma_f32_16x16x32_bf16(a0, *(const bf16x8*)(wb +  0), c, 0, 0, 0);
        c = __builtin_amdgcn_mfma_f32_16x16x32_bf16(a1, *(const bf16x8*)(wb + 32), c, 0, 0, 0);
        c = __builtin_amdgcn_mfma_f32_16x16x32_bf16(a2, *(const bf16x8*)(wb + 64), c, 0, 0, 0);
        c = __builtin_amdgcn_mfma_f32_16x16x32_bf16(a3, *(const bf16x8*)(wb + 96), c, 0, 0, 0);
        // scale rows by dinv, park in LDS (C rows != packable cols)
        #pragma unroll
        for (int r = 0; r < 4; ++r) {
            int row = (lane >> 4) * 4 + r;
            ct[row * 16 + ccol] = c[r] * dl[wid * 16 + row];
        }
        // repack: lane -> (row = l>>2, dword = l&3) = 4 consecutive cols
        int rrow = lane >> 2, rdw = lane & 3;
        f32x4 v = *(const f32x4*)&ct[rrow * 16 + rdw * 4];
        int w = __builtin_amdgcn_cvt_pk_fp8_f32(v[0], v[1], 0, false);
        w     = __builtin_amdgcn_cvt_pk_fp8_f32(v[2], v[3], w, true);
        int onode = wn0 + rrow;
        if (onode < n) gout[(size_t)onode * 32 + nt * 4 + rdw] = w;
    }
    (void)crow;
}

// out[i] = bf16( relu_opt( dinv[i]*( sum_{s in N(i)} g[s] + g[i] ) + b ) )  (fp8 g)
// 32 lanes x 1 dword (4 fp8) per row; lane>>5 picks edge of a pair; 4x unroll.
__global__ __launch_bounds__(256) void agg128_kernel(const void* __restrict__ g,
                                                     const int* __restrict__ rowptr,
                                                     const int* __restrict__ colarr,
                                                     const float* __restrict__ dinv,
                                                     const float* __restrict__ bias,
                                                     unsigned short* __restrict__ out,
                                                     int n, int relu) {
    int node = blockIdx.x * 4 + (threadIdx.x >> 6);
    if (node >= n) return;
    const int lane = threadIdx.x & 63;
    const int half = lane >> 5;        // edge-in-pair
    const int c    = lane & 31;        // dword index within row
    const int* gi = (const int*)g;     // row s -> gi[s*32 + c]
    const int beg = rowptr[node], end = rowptr[node + 1];
    float ax = 0.f, ay = 0.f, az = 0.f, aw = 0.f;
    int e = beg;
    for (; e + 8 <= end; e += 8) {
        int s0 = colarr[e     + half];
        int s1 = colarr[e + 2 + half];
        int s2 = colarr[e + 4 + half];
        int s3 = colarr[e + 6 + half];
        int w0 = gi[(size_t)s0 * 32 + c];
        int w1 = gi[(size_t)s1 * 32 + c];
        int w2 = gi[(size_t)s2 * 32 + c];
        int w3 = gi[(size_t)s3 * 32 + c];
        f32x2 l0 = __builtin_amdgcn_cvt_pk_f32_fp8(w0, false);
        f32x2 h0 = __builtin_amdgcn_cvt_pk_f32_fp8(w0, true);
        f32x2 l1 = __builtin_amdgcn_cvt_pk_f32_fp8(w1, false);
        f32x2 h1 = __builtin_amdgcn_cvt_pk_f32_fp8(w1, true);
        f32x2 l2 = __builtin_amdgcn_cvt_pk_f32_fp8(w2, false);
        f32x2 h2 = __builtin_amdgcn_cvt_pk_f32_fp8(w2, true);
        f32x2 l3 = __builtin_amdgcn_cvt_pk_f32_fp8(w3, false);
        f32x2 h3 = __builtin_amdgcn_cvt_pk_f32_fp8(w3, true);
        ax += (l0[0] + l1[0]) + (l2[0] + l3[0]);
        ay += (l0[1] + l1[1]) + (l2[1] + l3[1]);
        az += (h0[0] + h1[0]) + (h2[0] + h3[0]);
        aw += (h0[1] + h1[1]) + (h2[1] + h3[1]);
    }
    for (; e < end; e += 2) {
        int idx = e + half;
        int w = 0;
        if (idx < end) {
            int s = colarr[idx];
            w = gi[(size_t)s * 32 + c];
        }
        f32x2 lo = __builtin_amdgcn_cvt_pk_f32_fp8(w, false);
        f32x2 hi = __builtin_amdgcn_cvt_pk_f32_fp8(w, true);
        ax += lo[0]; ay += lo[1]; az += hi[0]; aw += hi[1];
    }
    ax += __shfl_xor(ax, 32);
    ay += __shfl_xor(ay, 32);
    az += __shfl_xor(az, 32);
    aw += __shfl_xor(aw, 32);
    if (lane < 32) {
        int wsv = gi[(size_t)node * 32 + lane];
        f32x2 slo = __builtin_amdgcn_cvt_pk_f32_fp8(wsv, false);
        f32x2 shi = __builtin_amdgcn_cvt_pk_f32_fp8(wsv, true);
        float4 b = ((const float4*)bias)[lane];
        float di = dinv[node];
        float ox = (ax + slo[0]) * di + b.x;
        float oy = (ay + slo[1]) * di + b.y;
        float oz = (az + shi[0]) * di + b.z;
        float ow = (aw + shi[1]) * di + b.w;
        if (relu) {
            ox = fmaxf(ox, 0.f); oy = fmaxf(oy, 0.f);
            oz = fmaxf(oz, 0.f); ow = fmaxf(ow, 0.f);
        }
        ushort4 o;
        o.x = f2bf(ox); o.y = f2bf(oy); o.z = f2bf(oz); o.w = f2bf(ow);
        ((ushort4*)(out + (size_t)node * 128))[lane] = o;
    }
}

// t[i] = dot(hb[i,:], W4[:,0]) * dinv[i]   (hb bf16)
__global__ void head_kernel(const unsigned short* __restrict__ hb,
                            const float* __restrict__ W4,
                            const float* __restrict__ dinv, float* __restrict__ t, int n) {
    int node = blockIdx.x * 4 + (threadIdx.x >> 6);
    if (node >= n) return;
    int lane = threadIdx.x & 63;
    ushort2 v = ((const ushort2*)(hb + (size_t)node * 128))[lane];
    float2 w = ((const float2*)W4)[lane];
    float p = bf2f(v.x) * w.x + bf2f(v.y) * w.y;
    #pragma unroll
    for (int off = 32; off; off >>= 1) p += __shfl_xor(p, off);
    if (lane == 0) t[node] = p * dinv[node];
}

// s[i] = dinv[i]*( sum t[s] + t[i] ) + b4
__global__ void aggs_kernel(const float* __restrict__ t, const int* __restrict__ rowptr,
                            const int* __restrict__ colarr, const float* __restrict__ dinv,
                            const float* __restrict__ b4, float* __restrict__ s, int n) {
    int i = blockIdx.x * 256 + threadIdx.x;
    if (i >= n) return;
    float acc = 0.f;
    int beg = rowptr[i], end = rowptr[i + 1];
    int e = beg;
    for (; e + 3 < end; e += 4) {
        acc += (t[colarr[e]] + t[colarr[e + 1]]) + (t[colarr[e + 2]] + t[colarr[e + 3]]);
    }
    for (; e < end; ++e) acc += t[colarr[e]];
    s[i] = (acc + t[i]) * dinv[i] + b4[0];
}

// batch is sorted: record each graph's node range
__global__ void bounds_kernel(const int* __restrict__ batch, int* __restrict__ gstart,
                              int* __restrict__ gend, int n) {
    int i = blockIdx.x * 256 + threadIdx.x;
    if (i >= n) return;
    int g = batch[i];
    if (i == 0     || batch[i - 1] != g) gstart[g] = i;
    if (i == n - 1 || batch[i + 1] != g) gend[g]   = i + 1;
}

// one wave per graph: mean over its node range + sigmoid, straight to d_out
__global__ void pool2_kernel(const float* __restrict__ sv, const int* __restrict__ gstart,
                             const int* __restrict__ gend, float* __restrict__ out, int ng) {
    int g = blockIdx.x * 4 + (threadIdx.x >> 6);
    if (g >= ng) return;
    int lane = threadIdx.x & 63;
    int beg = gstart[g], end = gend[g];
    float acc = 0.f;
    for (int i = beg + lane; i < end; i += 64) acc += sv[i];
    #pragma unroll
    for (int off = 32; off; off >>= 1) acc += __shfl_xor(acc, off);
    if (lane == 0) {
        float c = fmaxf((float)(end - beg), 1.0f);
        float v = acc / c;
        out[g] = 1.0f / (1.0f + expf(-v));
    }
}

extern "C" void kernel_launch(void* const* d_in, const int* in_sizes, int n_in,
                              void* d_out, int out_size, void* d_ws, size_t ws_size,
                              hipStream_t stream) {
    const float* x    = (const float*)d_in[0];
    const int*   eidx = (const int*)d_in[1];
    const int*   batch= (const int*)d_in[2];
    const float* W1 = (const float*)d_in[3];
    const float* b1 = (const float*)d_in[4];
    const float* W2 = (const float*)d_in[5];
    const float* b2 = (const float*)d_in[6];
    const float* W3 = (const float*)d_in[7];
    const float* b3 = (const float*)d_in[8];
    const float* W4 = (const float*)d_in[9];
    const float* b4 = (const float*)d_in[10];

    const int n  = in_sizes[0] / 6;
    const int e  = in_sizes[1] / 2;
    const int ng = out_size;
    const int* src = eidx;
    const int* dst = eidx + e;
    const int nbuk = (n + BKT - 1) / BKT;   // 1563 @ n=100k (MAXBUK cap)

    // workspace layout
    char* ws = (char*)d_ws;
    float* bufA   = (float*)ws; ws += (size_t)n * 128 * 4;   // xs / CSR scratch / hb
    void*  gbuf   = (void*)ws;  ws += (size_t)n * 128 * 4;   // ax / fp8 gout
    int*   colarr = (int*)ws;   ws += (size_t)e * 4;
    int*   rowptr = (int*)ws;   ws += ((size_t)n + 4) * 4;
    float* dinv   = (float*)ws; ws += (size_t)n * 4;
    float* t      = (float*)ws; ws += (size_t)n * 4;
    float* sv     = (float*)ws; ws += (size_t)n * 4;
    int*   gstart = (int*)ws;   ws += 1024;
    int*   gend   = (int*)ws;   ws += 1024;
    unsigned short* wtg2 = (unsigned short*)ws; ws += 128 * WTP * 2;
    unsigned short* wtg3 = (unsigned short*)ws; ws += 128 * WTP * 2;

    // CSR-build scratch in bufA's tail (dead before gemm1 writes hb there)
    char* tail = (char*)bufA;
    int* part    = (int*)(tail + (16u << 20));   // e ints (6.4MB)
    int* hmatT   = (int*)(tail + (24u << 20));   // nbuk*NCH ints
    int* totals  = (int*)(tail + (26u << 20));   // nbuk ints
    int* bukBase = (int*)(tail + (27u << 20));   // nbuk+1 ints

    float* xs = bufA;                       // [n,6] prescaled x
    float* ax = (float*)gbuf;               // [n,6] aggregated
    unsigned short* hb = (unsigned short*)bufA;  // [n,128] bf16 h (+64-row slack in 51MB buf)

    const int nb = (n + 255) / 256;
    const int nw = (n + 3) / 4;
    const int gb = (n + MB - 1) / MB;

    // ---- CSR build (no device-scope atomics) ----
    hist_bucket<<<NCH, 256, 0, stream>>>(dst, hmatT, e, nbuk);
    scan_chunks<<<(nbuk + 3) / 4, 256, 0, stream>>>(hmatT, totals, nbuk);
    scan_kernel<<<1, 1024, 0, stream>>>(totals, bukBase, nbuk);
    partition_kernel<<<NCH, 256, 0, stream>>>(src, dst, hmatT, bukBase, part, e, nbuk);
    bucket_csr<<<nbuk, 256, 0, stream>>>(part, bukBase, colarr, rowptr, dinv, n, e);

    // ---- weight prep (transposed bf16, padded) ----
    wconv_kernel<<<64, 256, 0, stream>>>(W2, wtg2);
    wconv_kernel<<<64, 256, 0, stream>>>(W3, wtg3);

    // ---- layer 1: prescale x, aggregate (6-dim), then GEMM -> bf16 h ----
    xscale_kernel<<<(n * 6 + 255) / 256, 256, 0, stream>>>(x, dinv, xs, n);
    aggx_kernel<<<nb, 256, 0, stream>>>(xs, rowptr, colarr, dinv, ax, n);
    gemm1_kernel<<<(n * 128 + 255) / 256, 256, 0, stream>>>(ax, W1, b1, hb, n);

    // ---- layer 2 ----
    gemm128_mfma<<<gb, 256, 0, stream>>>(hb, wtg2, dinv, (int*)gbuf, n);
    agg128_kernel<<<nw, 256, 0, stream>>>(gbuf, rowptr, colarr, dinv, b2, hb, n, 1);

    // ---- layer 3 ----
    gemm128_mfma<<<gb, 256, 0, stream>>>(hb, wtg3, dinv, (int*)gbuf, n);
    agg128_kernel<<<nw, 256, 0, stream>>>(gbuf, rowptr, colarr, dinv, b3, hb, n, 1);

    // ---- layer 4: project to scalar, aggregate ----
    head_kernel<<<nw, 256, 0, stream>>>(hb, W4, dinv, t, n);
    aggs_kernel<<<nb, 256, 0, stream>>>(t, rowptr, colarr, dinv, b4, sv, n);

    // ---- pool: sorted batch -> segment bounds + per-graph wave mean ----
    hipMemsetAsync(gstart, 0, 2048, stream);
    bounds_kernel<<<nb, 256, 0, stream>>>(batch, gstart, gend, n);
    pool2_kernel<<<(ng + 3) / 4, 256, 0, stream>>>(sv, gstart, gend, (float*)d_out, ng);
}